// Round 18
// baseline (637.032 us; speedup 1.0000x reference)
//
#include <hip/hip_runtime.h>
#include <hip/hip_bf16.h>
#include <math.h>

typedef unsigned int u32;
typedef unsigned short u16;
using bf16x8 = __attribute__((ext_vector_type(8))) short;
using f32x4 = __attribute__((ext_vector_type(4))) float;

#define MFMA_BF16(a, b, c) __builtin_amdgcn_mfma_f32_16x16x32_bf16((a), (b), (c), 0, 0, 0)
#define VMCNT8() asm volatile("s_waitcnt vmcnt(8)" ::: "memory")
#define VMCNT6() asm volatile("s_waitcnt vmcnt(6)" ::: "memory")
#define VMCNT0() asm volatile("s_waitcnt vmcnt(0)" ::: "memory")
#define LGKM0() asm volatile("s_waitcnt lgkmcnt(0)" ::: "memory")
#define SBAR() __builtin_amdgcn_s_barrier()
#define SCHED0() __builtin_amdgcn_sched_barrier(0)

constexpr int kS = 2048, kD = 1024, kH = 16, kE = 8, kFF = 4096;
constexpr int kSlotCap = 5120;  // 40 tiles x 128 (128-aligned expert bases)
constexpr int kMaxTiles = 40;
constexpr int kChunk = 8;       // kt tiles per attn block (512 tokens)

// ---------- numeric helpers ----------
__device__ __forceinline__ u16 bf16_rne(float f) {
  u32 u = __float_as_uint(f);
  u32 r = (u + 0x7fffu + ((u >> 16) & 1u)) >> 16;
  return (u16)r;
}
__device__ __forceinline__ float bf16_f32(u16 h) { return __uint_as_float(((u32)h) << 16); }
__device__ __forceinline__ u32 pack_hl(float x) {
  u16 hi = bf16_rne(x);
  u16 lo = bf16_rne(x - bf16_f32(hi));
  return ((u32)lo << 16) | (u32)hi;
}
__device__ __forceinline__ void unpack8(const u32* t, bf16x8& h, bf16x8& l) {
#pragma unroll
  for (int j = 0; j < 8; j++) {
    h[j] = (short)(t[j] & 0xffffu);
    l[j] = (short)(t[j] >> 16);
  }
}
__device__ __forceinline__ void gload_lds16(const void* g, void* l) {
  __builtin_amdgcn_global_load_lds((const __attribute__((address_space(1))) u32*)g,
                                   (__attribute__((address_space(3))) u32*)l, 16, 0, 0);
}
// packed f32x2 -> bf16x2 (RNE), single HW instruction
__device__ __forceinline__ u32 cvtpk(float a, float b) {
  u32 r;
  asm("v_cvt_pk_bf16_f32 %0, %1, %2" : "=v"(r) : "v"(a), "v"(b));
  return r;
}

// ---------- weight packs (attention path only) ----------
__global__ __launch_bounds__(256) void pack_dp3(const float* __restrict__ Wq,
                                                const float* __restrict__ Wk,
                                                const float* __restrict__ Wv,
                                                u16* __restrict__ o) {
  int i = blockIdx.x * 256 + threadIdx.x;
  if (i >= 3072 * 1024) return;
  int n = i >> 10, k = i & 1023;
  float v = (n < 1024) ? Wq[i] : (n < 2048) ? Wk[i - 1024 * 1024] : Wv[i - 2048 * 1024];
  u16 hi = bf16_rne(v);
  u16 lo = bf16_rne(v - bf16_f32(hi));
  size_t b = (size_t)n * 2048 + (size_t)(k >> 5) * 64 + (k & 31);
  o[b] = hi;
  o[b + 32] = lo;
}
__global__ __launch_bounds__(256) void pack_dp1(const float* __restrict__ W,
                                                u16* __restrict__ o, int n_elem) {
  int i = blockIdx.x * 256 + threadIdx.x;
  if (i >= n_elem) return;
  int k = i & 1023, n = i >> 10;
  float v = W[i];
  u16 hi = bf16_rne(v);
  u16 lo = bf16_rne(v - bf16_f32(hi));
  size_t b = (size_t)n * 2048 + (size_t)(k >> 5) * 64 + (k & 31);
  o[b] = hi;
  o[b + 32] = lo;
}

// ---------- RMSNorm. MODE 0: dual-plane u16. MODE 1: f32 + bf16 ----------
template <int MODE>
__global__ __launch_bounds__(256) void rmsnorm_kernel(
    const float* __restrict__ x, const float* __restrict__ scale,
    u16* __restrict__ odp, float* __restrict__ of32, u16* __restrict__ ob16) {
  const int s = blockIdx.x;
  const float* row = x + (size_t)s * kD;
  const int c = threadIdx.x * 4;
  float4 v = *(const float4*)(row + c);
  float ss = v.x * v.x + v.y * v.y + v.z * v.z + v.w * v.w;
#pragma unroll
  for (int m = 32; m; m >>= 1) ss += __shfl_xor(ss, m);
  __shared__ float wsum[4];
  if ((threadIdx.x & 63) == 0) wsum[threadIdx.x >> 6] = ss;
  __syncthreads();
  float tot = wsum[0] + wsum[1] + wsum[2] + wsum[3];
  float rinv = 1.0f / sqrtf(tot * (1.0f / kD) + 1e-5f);
  float4 sc = *(const float4*)(scale + c);
  float n[4] = {v.x * rinv * sc.x, v.y * rinv * sc.y, v.z * rinv * sc.z, v.w * rinv * sc.w};
  if (MODE == 0) {
    u16 hv[4], lv[4];
#pragma unroll
    for (int j = 0; j < 4; j++) {
      hv[j] = bf16_rne(n[j]);
      lv[j] = bf16_rne(n[j] - bf16_f32(hv[j]));
    }
    u16* o = odp + (size_t)s * 2048 + (size_t)(c >> 5) * 64 + (c & 31);
    *(uint2*)o = *(uint2*)hv;
    *(uint2*)(o + 32) = *(uint2*)lv;
  } else {
    *(float4*)(of32 + (size_t)s * kD + c) = make_float4(n[0], n[1], n[2], n[3]);
    u16* o = ob16 + (size_t)s * kD + c;
    o[0] = bf16_rne(n[0]); o[1] = bf16_rne(n[1]); o[2] = bf16_rne(n[2]); o[3] = bf16_rne(n[3]);
  }
}

// ---------- split-bf16 3-term GEMM (attention path), counted-vmcnt 2-phase ----------
template <int APK, int OUT>
__global__ __launch_bounds__(256) void gemm_dp(
    const void* __restrict__ Av, const u16* __restrict__ Bdp,
    const float* __restrict__ resid, int K,
    u32* __restrict__ oq, u32* __restrict__ ok, u32* __restrict__ ov,
    float* __restrict__ of) {
  __shared__ u16 As[2][128 * 64];
  __shared__ u16 Bs[2][128 * 64];
  const int tid = threadIdx.x, w = tid >> 6, l = tid & 63;
  const int m0 = blockIdx.y * 128, n0 = blockIdx.x * 128;
  const int wr = (w >> 1) * 64, wc = (w & 1) * 64;
  const char* Ab = (const char*)Av;
  const char* Bb = (const char*)Bdp;
  const size_t rowb = (size_t)K * 4;

  size_t asrc[4], bsrc[4];
  int dst[4];
#pragma unroll
  for (int i = 0; i < 4; i++) {
    int fl = i * 256 + tid;
    int row = fl >> 3, cb = fl & 7;
    size_t coff = (size_t)((cb ^ (row & 7)) * 16);
    asrc[i] = (size_t)(m0 + row) * rowb + coff;
    bsrc[i] = (size_t)(n0 + row) * rowb + coff;
    dst[i] = fl * 16;
  }

  f32x4 zero = {0.f, 0.f, 0.f, 0.f};
  f32x4 acc[4][4];
#pragma unroll
  for (int i = 0; i < 4; i++)
#pragma unroll
    for (int j = 0; j < 4; j++) acc[i][j] = zero;

  auto stage = [&](int buf, int s) {
    const char* ap = Ab + (size_t)s * 128;
    const char* bp = Bb + (size_t)s * 128;
#pragma unroll
    for (int i = 0; i < 4; i++) {
      gload_lds16(ap + asrc[i], (char*)&As[buf][0] + dst[i]);
      gload_lds16(bp + bsrc[i], (char*)&Bs[buf][0] + dst[i]);
    }
  };

  const int NS = K / 32;
  stage(0, 0);
  for (int s = 0; s < NS; s++) {
    const int cur = s & 1;
    const bool lastit = (s == NS - 1);
    if (!lastit) stage(cur ^ 1, s + 1);
    if (!lastit) VMCNT8(); else VMCNT0();
    SBAR();
    SCHED0();
    bf16x8 ah[4], al[4], bh[4], bl[4];
    const int g = l >> 4;
    if (APK) {
      const u32* At = (const u32*)&As[cur][0];
#pragma unroll
      for (int mi = 0; mi < 4; mi++) {
        int row = wr + mi * 16 + (l & 15);
        u32 t[8];
        *(uint4*)t = *(const uint4*)&At[row * 32 + (((2 * g) ^ (row & 7)) * 4)];
        *(uint4*)(t + 4) = *(const uint4*)&At[row * 32 + (((2 * g + 1) ^ (row & 7)) * 4)];
        unpack8(t, ah[mi], al[mi]);
      }
    } else {
#pragma unroll
      for (int mi = 0; mi < 4; mi++) {
        int row = wr + mi * 16 + (l & 15);
        ah[mi] = *(const bf16x8*)&As[cur][row * 64 + ((g ^ (row & 7)) * 8)];
        al[mi] = *(const bf16x8*)&As[cur][row * 64 + (((4 + g) ^ (row & 7)) * 8)];
      }
    }
#pragma unroll
    for (int ni = 0; ni < 4; ni++) {
      int row = wc + ni * 16 + (l & 15);
      bh[ni] = *(const bf16x8*)&Bs[cur][row * 64 + ((g ^ (row & 7)) * 8)];
      bl[ni] = *(const bf16x8*)&Bs[cur][row * 64 + (((4 + g) ^ (row & 7)) * 8)];
    }
#pragma unroll
    for (int mi = 0; mi < 4; mi++)
#pragma unroll
      for (int ni = 0; ni < 4; ni++) {
        f32x4 c = acc[mi][ni];
        c = MFMA_BF16(al[mi], bh[ni], c);
        c = MFMA_BF16(ah[mi], bl[ni], c);
        c = MFMA_BF16(ah[mi], bh[ni], c);
        acc[mi][ni] = c;
      }
    SCHED0();
    if (!lastit) SBAR();
  }

  if (OUT == 0) {
    u32* dstp;
    int nb;
    if (n0 < 1024) { dstp = oq; nb = n0; }
    else if (n0 < 2048) { dstp = ok; nb = n0 - 1024; }
    else { dstp = ov; nb = n0 - 2048; }
#pragma unroll
    for (int mi = 0; mi < 4; mi++)
#pragma unroll
      for (int ni = 0; ni < 4; ni++)
#pragma unroll
        for (int r = 0; r < 4; r++) {
          int row = m0 + wr + mi * 16 + ((l >> 4) << 2) + r;
          int col = nb + wc + ni * 16 + (l & 15);
          dstp[(size_t)row * 1024 + col] = pack_hl(acc[mi][ni][r]);
        }
  } else {
#pragma unroll
    for (int mi = 0; mi < 4; mi++)
#pragma unroll
      for (int ni = 0; ni < 4; ni++)
#pragma unroll
        for (int r = 0; r < 4; r++) {
          int row = m0 + wr + mi * 16 + ((l >> 4) << 2) + r;
          int col = n0 + wc + ni * 16 + (l & 15);
          of[(size_t)row * 1024 + col] = resid[(size_t)row * 1024 + col] + acc[mi][ni][r];
        }
  }
}

// ---------- flash attention, kt-chunked (validated round-6 version) ----------
__global__ __launch_bounds__(256) void attn_kernel(
    const u32* __restrict__ Qp, const u32* __restrict__ Kp, const u32* __restrict__ Vp,
    float* __restrict__ Opart, float* __restrict__ mpart, float* __restrict__ lpart) {
  constexpr int LDK = 68;
  __shared__ u32 Ks[64 * LDK];
  __shared__ u32 Vs[64 * LDK];
  __shared__ u32 Ps[64 * LDK];
  const int tid = threadIdx.x, w = tid >> 6, l = tid & 63;
  int b = blockIdx.x, qt, c;
  if (b < 8) { qt = b; c = 0; }
  else if (b < 24) { qt = 8 + ((b - 8) >> 1); c = (b - 8) & 1; }
  else if (b < 48) { qt = 16 + (b - 24) / 3; c = (b - 24) % 3; }
  else { qt = 24 + ((b - 48) >> 2); c = (b - 48) & 3; }
  const int hh = blockIdx.y;
  const int q0 = qt * 64, hc = hh * 64;
  const int kt0 = c * kChunk;
  const int kt1 = min(kt0 + kChunk, qt + 1);

  bf16x8 qh[2], ql[2];
  {
    const int qrow = q0 + w * 16 + (l & 15);
#pragma unroll
    for (int kk = 0; kk < 2; kk++) {
      u32 t[8];
      const u32* p = Qp + (size_t)qrow * kD + hc + kk * 32 + ((l >> 4) << 3);
      *(uint4*)t = *(const uint4*)p;
      *(uint4*)(t + 4) = *(const uint4*)(p + 4);
      unpack8(t, qh[kk], ql[kk]);
    }
  }
  float mrun[4], lrun[4];
  f32x4 zero = {0.f, 0.f, 0.f, 0.f};
  f32x4 oacc[4];
#pragma unroll
  for (int r = 0; r < 4; r++) { mrun[r] = -3.0e38f; lrun[r] = 0.f; }
#pragma unroll
  for (int vb = 0; vb < 4; vb++) oacc[vb] = zero;

  const int trow = tid >> 2, c0v = (tid & 3) * 16;
  const u32* gKb = Kp + hc + c0v;
  const u32* gVb = Vp + hc + c0v;
  uint4 kr[4], vr[4];
  {
    const u32* gK = gKb + (size_t)(kt0 * 64 + trow) * kD;
    kr[0] = *(const uint4*)gK; kr[1] = *(const uint4*)(gK + 4);
    kr[2] = *(const uint4*)(gK + 8); kr[3] = *(const uint4*)(gK + 12);
    const u32* gV = gVb + (size_t)(kt0 * 64 + trow) * kD;
    vr[0] = *(const uint4*)gV; vr[1] = *(const uint4*)(gV + 4);
    vr[2] = *(const uint4*)(gV + 8); vr[3] = *(const uint4*)(gV + 12);
  }

  for (int kt = kt0; kt < kt1; kt++) {
    {
      u32* sK = Ks + trow * LDK + c0v;
      *(uint4*)sK = kr[0]; *(uint4*)(sK + 4) = kr[1];
      *(uint4*)(sK + 8) = kr[2]; *(uint4*)(sK + 12) = kr[3];
#pragma unroll
      for (int j = 0; j < 4; j++) {
        Vs[(c0v + j * 4 + 0) * LDK + trow] = vr[j].x;
        Vs[(c0v + j * 4 + 1) * LDK + trow] = vr[j].y;
        Vs[(c0v + j * 4 + 2) * LDK + trow] = vr[j].z;
        Vs[(c0v + j * 4 + 3) * LDK + trow] = vr[j].w;
      }
    }
    __syncthreads();
    if (kt + 1 < kt1) {
      const u32* gK = gKb + (size_t)((kt + 1) * 64 + trow) * kD;
      kr[0] = *(const uint4*)gK; kr[1] = *(const uint4*)(gK + 4);
      kr[2] = *(const uint4*)(gK + 8); kr[3] = *(const uint4*)(gK + 12);
      const u32* gV = gVb + (size_t)((kt + 1) * 64 + trow) * kD;
      vr[0] = *(const uint4*)gV; vr[1] = *(const uint4*)(gV + 4);
      vr[2] = *(const uint4*)(gV + 8); vr[3] = *(const uint4*)(gV + 12);
    }

    f32x4 sfr[4];
#pragma unroll
    for (int kb = 0; kb < 4; kb++) {
      f32x4 sa = zero;
#pragma unroll
      for (int kk = 0; kk < 2; kk++) {
        u32 t[8];
        bf16x8 kh, kl;
        const u32* p = Ks + (kb * 16 + (l & 15)) * LDK + kk * 32 + ((l >> 4) << 3);
        *(uint4*)t = *(const uint4*)p;
        *(uint4*)(t + 4) = *(const uint4*)(p + 4);
        unpack8(t, kh, kl);
        sa = MFMA_BF16(ql[kk], kl, sa);
        sa = MFMA_BF16(ql[kk], kh, sa);
        sa = MFMA_BF16(qh[kk], kl, sa);
        sa = MFMA_BF16(qh[kk], kh, sa);
      }
      sfr[kb] = sa * 0.125f;
    }
    if (kt == qt) {
#pragma unroll
      for (int kb = 0; kb < 4; kb++) {
        int t = kt * 64 + kb * 16 + (l & 15);
#pragma unroll
        for (int r = 0; r < 4; r++) {
          int qq = q0 + w * 16 + ((l >> 4) << 2) + r;
          if (t > qq) sfr[kb][r] = -3.0e38f;
        }
      }
    }
#pragma unroll
    for (int r = 0; r < 4; r++) {
      float mx = fmaxf(fmaxf(sfr[0][r], sfr[1][r]), fmaxf(sfr[2][r], sfr[3][r]));
#pragma unroll
      for (int mm = 1; mm < 16; mm <<= 1) mx = fmaxf(mx, __shfl_xor(mx, mm));
      float mnew = fmaxf(mrun[r], mx);
      float sf = __expf(mrun[r] - mnew);
      mrun[r] = mnew;
      float rs = 0.f;
#pragma unroll
      for (int kb = 0; kb < 4; kb++) {
        float p = __expf(sfr[kb][r] - mnew);
        sfr[kb][r] = p;
        rs += p;
      }
#pragma unroll
      for (int mm = 1; mm < 16; mm <<= 1) rs += __shfl_xor(rs, mm);
      lrun[r] = lrun[r] * sf + rs;
#pragma unroll
      for (int vb = 0; vb < 4; vb++) oacc[vb][r] *= sf;
    }
#pragma unroll
    for (int kb = 0; kb < 4; kb++)
#pragma unroll
      for (int r = 0; r < 4; r++)
        Ps[(w * 16 + ((l >> 4) << 2) + r) * LDK + kb * 16 + (l & 15)] = pack_hl(sfr[kb][r]);
#pragma unroll
    for (int ks = 0; ks < 2; ks++) {
      bf16x8 ph, pl;
      {
        u32 t[8];
        const u32* pp = Ps + (w * 16 + (l & 15)) * LDK + ks * 32 + ((l >> 4) << 3);
        *(uint4*)t = *(const uint4*)pp;
        *(uint4*)(t + 4) = *(const uint4*)(pp + 4);
        unpack8(t, ph, pl);
      }
#pragma unroll
      for (int vb = 0; vb < 4; vb++) {
        u32 t2[8];
        bf16x8 vh, vl;
        const u32* pv = Vs + (vb * 16 + (l & 15)) * LDK + ks * 32 + ((l >> 4) << 3);
        *(uint4*)t2 = *(const uint4*)pv;
        *(uint4*)(t2 + 4) = *(const uint4*)(pv + 4);
        unpack8(t2, vh, vl);
        f32x4 cc = oacc[vb];
        cc = MFMA_BF16(pl, vl, cc);
        cc = MFMA_BF16(pl, vh, cc);
        cc = MFMA_BF16(ph, vl, cc);
        cc = MFMA_BF16(ph, vh, cc);
        oacc[vb] = cc;
      }
    }
    __syncthreads();
  }

  const int p = (qt * 16 + hh) * 4 + c;
  float* Po = Opart + (size_t)p * 4096;
#pragma unroll
  for (int vb = 0; vb < 4; vb++)
#pragma unroll
    for (int r = 0; r < 4; r++) {
      int rl = w * 16 + ((l >> 4) << 2) + r;
      int cl = vb * 16 + (l & 15);
      Po[rl * 64 + cl] = oacc[vb][r];
    }
  if ((l & 15) == 0) {
#pragma unroll
    for (int r = 0; r < 4; r++) {
      int rl = w * 16 + ((l >> 4) << 2) + r;
      mpart[p * 64 + rl] = mrun[r];
      lpart[p * 64 + rl] = lrun[r];
    }
  }
}

// ---------- merge chunk partials -> packed ctx ----------
__global__ __launch_bounds__(256) void attn_merge(
    const float* __restrict__ Opart, const float* __restrict__ mpart,
    const float* __restrict__ lpart, u32* __restrict__ Op) {
  const int qt = blockIdx.x, hh = blockIdx.y;
  const int nch = (qt + kChunk) >> 3;
  const int t = threadIdx.x;
  const int row = t >> 2;
  const int c0 = (t & 3) * 16;
  const int pbase = (qt * 16 + hh) * 4;
  float M = -3.0e38f;
  for (int c = 0; c < nch; c++) M = fmaxf(M, mpart[(pbase + c) * 64 + row]);
  float den = 0.f;
  float acc[16];
#pragma unroll
  for (int j = 0; j < 16; j++) acc[j] = 0.f;
  for (int c = 0; c < nch; c++) {
    float wgt = __expf(mpart[(pbase + c) * 64 + row] - M);
    den += wgt * lpart[(pbase + c) * 64 + row];
    const float* po = Opart + (size_t)(pbase + c) * 4096 + row * 64 + c0;
#pragma unroll
    for (int j = 0; j < 16; j += 4) {
      float4 v = *(const float4*)(po + j);
      acc[j] += wgt * v.x; acc[j + 1] += wgt * v.y;
      acc[j + 2] += wgt * v.z; acc[j + 3] += wgt * v.w;
    }
  }
  float inv = 1.f / den;
  u32* dst = Op + (size_t)(qt * 64 + row) * kD + hh * 64 + c0;
#pragma unroll
  for (int j = 0; j < 16; j++) dst[j] = pack_hl(acc[j] * inv);
}

// ---------- router ----------
__global__ __launch_bounds__(256) void router_kernel(
    const float* __restrict__ normed, const float* __restrict__ Wg,
    float* __restrict__ probs, float* __restrict__ gates,
    int* __restrict__ experts, int* __restrict__ counts) {
  const int w = threadIdx.x >> 6, l = threadIdx.x & 63;
  const int s = blockIdx.x * 4 + w;
  float lg[kE];
  const float* row = normed + (size_t)s * kD;
#pragma unroll
  for (int e = 0; e < kE; e++) {
    const float* wg = Wg + (size_t)e * kD;
    float a = 0.f;
    for (int d = l; d < kD; d += 64) a += row[d] * wg[d];
#pragma unroll
    for (int m = 32; m; m >>= 1) a += __shfl_xor(a, m);
    lg[e] = a;
  }
  if (l == 0) {
    float mx = lg[0];
#pragma unroll
    for (int e = 1; e < kE; e++) mx = fmaxf(mx, lg[e]);
    float p[kE], sum = 0.f;
#pragma unroll
    for (int e = 0; e < kE; e++) { p[e] = __expf(lg[e] - mx); sum += p[e]; }
    float inv = 1.f / sum;
#pragma unroll
    for (int e = 0; e < kE; e++) { p[e] *= inv; probs[(size_t)s * kE + e] = p[e]; }
    int i1 = 0;
#pragma unroll
    for (int e = 1; e < kE; e++) if (lg[e] > lg[i1]) i1 = e;
    int i2 = (i1 == 0) ? 1 : 0;
#pragma unroll
    for (int e = 0; e < kE; e++) if (e != i1 && lg[e] > lg[i2]) i2 = e;
    float den = 1.f / (p[i1] + p[i2]);
    gates[s * 2] = p[i1] * den;
    gates[s * 2 + 1] = p[i2] * den;
    experts[s * 2] = i1;
    experts[s * 2 + 1] = i2;
    atomicAdd(&counts[i1], 1);
    atomicAdd(&counts[i2], 1);
  }
}

__global__ void moe_init(int* counts) {
  if (threadIdx.x < kE) counts[threadIdx.x] = 0;
}
__global__ void moe_scan(const int* __restrict__ counts, int* __restrict__ ebase,
                         int* __restrict__ cursor, int2* __restrict__ tmap) {
  if (threadIdx.x == 0) {
    int acc = 0, t = 0;
    for (int e = 0; e < kE; e++) {
      ebase[e] = acc;
      cursor[e] = acc;
      int nt = (counts[e] + 127) >> 7;
      for (int i = 0; i < nt; i++) tmap[t++] = make_int2(e, i * 128);
      acc += nt << 7;
    }
    ebase[kE] = acc;
    for (; t < kMaxTiles; t++) tmap[t] = make_int2(-1, 0);
  }
}
__global__ void moe_fill(const int* __restrict__ experts, int* __restrict__ cursor,
                         int* __restrict__ slot_list, int* __restrict__ slot_of) {
  int s = blockIdx.x * 256 + threadIdx.x;
  if (s >= kS) return;
  for (int k = 0; k < 2; k++) {
    int e = experts[s * 2 + k];
    int pos = atomicAdd(&cursor[e], 1);
    slot_list[pos] = s;
    slot_of[s * 2 + k] = pos;
  }
}

// ---------- MoE GEMM A: fused gelu, f32 weights DIRECT, BK=32 (round-10/11/13/15/17 validated) ----------
__global__ __launch_bounds__(256) void moe_mmA(
    const u16* __restrict__ A, const float* __restrict__ Wi, const float* __restrict__ Wv2,
    const int* __restrict__ slot_list, const int* __restrict__ counts,
    const int* __restrict__ ebase, const int2* __restrict__ tmap,
    u16* __restrict__ H) {
  int2 tm = tmap[blockIdx.y];
  const int e = tm.x;
  if (e < 0) return;
  const int base = ebase[e], Me = counts[e], m0 = tm.y;
  const int n0 = blockIdx.x * 128;  // interleaved col base (0..8191)
  __shared__ u16 As[2][64 * 64];    // 8 KB per buffer
  __shared__ float Bsf[2][128 * 32];  // 16 KB per buffer
  const int tid = threadIdx.x, w = tid >> 6, l = tid & 63;
  const int wr = (w >> 1) * 64, wc = (w & 1) * 64;
  const char* Ab = (const char*)A;

  size_t asrc[2];
  int adst[2];
#pragma unroll
  for (int i = 0; i < 2; i++) {
    int fl = i * 256 + tid;
    int lrow = fl >> 3, sl = fl & 7;
    int sp = sl ^ (lrow & 7);
    int t = 2 * lrow + (sp >> 2);
    int cbl = sp & 3;
    int mr = m0 + t;
    if (mr > Me - 1) mr = Me - 1;
    int ar = slot_list[base + mr];
    asrc[i] = (size_t)ar * 2048 + (size_t)cbl * 16;
    adst[i] = fl * 16;
  }
  const char* bptr[4];
  int bdst[4];
#pragma unroll
  for (int i = 0; i < 4; i++) {
    int fl = i * 256 + tid;
    int row = fl >> 3, sl = fl & 7;
    int sp = sl ^ (row & 7);
    int nn = n0 + row;
    const float* srcT = (nn & 1) ? Wv2 : Wi;
    bptr[i] = (const char*)(srcT + ((size_t)e * 4096 + (nn >> 1)) * 1024) + sp * 16;
    bdst[i] = fl * 16;
  }

  const int g = l >> 4;
  int aoff[4], boff0[4], boff1[4];
#pragma unroll
  for (int mi = 0; mi < 4; mi++) {
    int t = wr + mi * 16 + (l & 15);
    int lr = t >> 1;
    int sl = (((t & 1) << 2) | g) ^ (lr & 7);
    aoff[mi] = lr * 128 + sl * 16;
  }
#pragma unroll
  for (int ni = 0; ni < 4; ni++) {
    int rr = wc + ni * 16 + (l & 15);
    boff0[ni] = rr * 128 + (((2 * g) ^ (rr & 7)) * 16);
    boff1[ni] = rr * 128 + (((2 * g + 1) ^ (rr & 7)) * 16);
  }

  f32x4 zero = {0.f, 0.f, 0.f, 0.f};
  f32x4 acc[4][4];
#pragma unroll
  for (int i = 0; i < 4; i++)
#pragma unroll
    for (int j = 0; j < 4; j++) acc[i][j] = zero;

  auto stage = [&](int buf, int s) {
    const size_t soA = (size_t)s * 64;
    const size_t soB = (size_t)s * 128;
#pragma unroll
    for (int i = 0; i < 2; i++)
      gload_lds16(Ab + soA + asrc[i], (char*)&As[buf][0] + adst[i]);
#pragma unroll
    for (int i = 0; i < 4; i++)
      gload_lds16(bptr[i] + soB, (char*)&Bsf[buf][0] + bdst[i]);
  };

  const int NS = kD / 32;  // 32
  stage(0, 0);
  for (int s = 0; s < NS; s++) {
    const int cur = s & 1;
    const bool lastit = (s == NS - 1);
    if (!lastit) stage(cur ^ 1, s + 1);
    if (!lastit) VMCNT6(); else VMCNT0();
    SBAR();
    SCHED0();
    const char* Ac = (const char*)&As[cur][0];
    const char* Bc = (const char*)&Bsf[cur][0];
    bf16x8 af[4], bfr[4];
#pragma unroll
    for (int mi = 0; mi < 4; mi++) af[mi] = *(const bf16x8*)(Ac + aoff[mi]);
#pragma unroll
    for (int ni = 0; ni < 4; ni++) {
      float4 f0 = *(const float4*)(Bc + boff0[ni]);
      float4 f1 = *(const float4*)(Bc + boff1[ni]);
      u32 pk[4];
      pk[0] = cvtpk(f0.x, f0.y);
      pk[1] = cvtpk(f0.z, f0.w);
      pk[2] = cvtpk(f1.x, f1.y);
      pk[3] = cvtpk(f1.z, f1.w);
      bfr[ni] = *(bf16x8*)pk;
    }
#pragma unroll
    for (int mi = 0; mi < 4; mi++)
#pragma unroll
      for (int ni = 0; ni < 4; ni++) acc[mi][ni] = MFMA_BF16(af[mi], bfr[ni], acc[mi][ni]);
    SCHED0();
    if (!lastit) SBAR();
  }

#pragma unroll
  for (int mi = 0; mi < 4; mi++)
#pragma unroll
    for (int r = 0; r < 4; r++) {
      int ml = m0 + wr + mi * 16 + ((l >> 4) << 2) + r;
      if (ml >= Me) continue;
      size_t rb = (size_t)(base + ml) * 4096;
#pragma unroll
      for (int ni = 0; ni < 4; ni++) {
        int col = n0 + wc + ni * 16 + (l & 15);
        float v0 = acc[mi][ni][r];
        float pv = __shfl_xor(v0, 1);
        if ((l & 1) == 0) {
          float ge = 0.5f * v0 * (1.0f + erff(v0 * 0.70710678118654752f));
          H[rb + (col >> 1)] = bf16_rne(ge * pv);
        }
      }
    }
}

// ---------- MoE GEMM 2: N=128, reg-staged single-barrier pipeline ----------
// Widened from N=64 (round-14/15 validated pipeline): per step 16 MFMA/wave vs 8
// at ~same latency-bound step cost; halves block count and A-panel traffic.
// A (bf16 H, 128 rows x 32/step): thread srow=tid>>1, sh=tid&1 (round-14 map).
// B (f32 W_out -> bf16, 128 rows x 32/step): thread brow=tid>>1, sh=tid&1,
// 16 f32 -> cvtpk -> 2x ds_write_b128 (round-16 mmA's validated B scheme).
// LDS 32 KB total; paired-row 0-conflict layout both operands.
__global__ __launch_bounds__(256) void moe_mm2(
    const u16* __restrict__ H, const float* __restrict__ Wo_f,
    const int* __restrict__ counts, const int* __restrict__ ebase,
    const int2* __restrict__ tmap, float* __restrict__ eo) {
  int2 tm = tmap[blockIdx.y];
  const int e = tm.x;
  if (e < 0) return;
  const int base = ebase[e], Me = counts[e], m0 = tm.y;
  const int n0 = blockIdx.x * 128;
  __shared__ u16 As[2][64 * 64];  // 8 KB per buffer (128 tile rows paired)
  __shared__ u16 Bs[2][64 * 64];  // 8 KB per buffer (128 n-rows paired)
  const int tid = threadIdx.x, w = tid >> 6, l = tid & 63;
  const int wr = (w >> 1) * 64, wc = (w & 1) * 64;

  // A staging: row srow = tid>>1 (0..127), k-half sh = tid&1 (16 bf16)
  const int srow = tid >> 1, sh = tid & 1;
  int mrA = m0 + srow;
  if (mrA > Me - 1) mrA = Me - 1;
  const u16* agp = H + (size_t)(base + mrA) * 4096 + sh * 16;  // +s*32 per step
  const int wlA = srow >> 1;
  const int awo0 = wlA * 128 + (((((srow & 1) << 2) | (sh * 2)) ^ (wlA & 7)) * 16);
  const int awo1 = wlA * 128 + (((((srow & 1) << 2) | (sh * 2 + 1)) ^ (wlA & 7)) * 16);
  // B staging: n-row brow = tid>>1 (0..127), k-half sh (16 f32 -> 2 bf16 chunks)
  const int brow = srow;
  const float* bgp = Wo_f + ((size_t)e * 1024 + n0 + brow) * 4096 + sh * 16;  // +s*32
  const int wlB = brow >> 1;
  const int bwo0 = wlB * 128 + (((((brow & 1) << 2) | (sh * 2)) ^ (wlB & 7)) * 16);
  const int bwo1 = wlB * 128 + (((((brow & 1) << 2) | (sh * 2 + 1)) ^ (wlB & 7)) * 16);

  const int g = l >> 4;
  int aoff[4], boff[4];
#pragma unroll
  for (int mi = 0; mi < 4; mi++) {
    int t = wr + mi * 16 + (l & 15);
    int lr = t >> 1;
    aoff[mi] = lr * 128 + (((((t & 1) << 2) | g) ^ (lr & 7)) * 16);
  }
#pragma unroll
  for (int ni = 0; ni < 4; ni++) {
    int t = wc + ni * 16 + (l & 15);
    int lr = t >> 1;
    boff[ni] = lr * 128 + (((((t & 1) << 2) | g) ^ (lr & 7)) * 16);
  }

  f32x4 zero = {0.f, 0.f, 0.f, 0.f};
  f32x4 acc[4][4];
#pragma unroll
  for (int i = 0; i < 4; i++)
#pragma unroll
    for (int j = 0; j < 4; j++) acc[i][j] = zero;

  // prologue: stage step 0 into buf 0
  uint4 a0 = *(const uint4*)agp;
  uint4 a1 = *(const uint4*)(agp + 8);
  float4 b0 = *(const float4*)bgp;
  float4 b1 = *(const float4*)(bgp + 4);
  float4 b2 = *(const float4*)(bgp + 8);
  float4 b3 = *(const float4*)(bgp + 12);
  {
    *(uint4*)((char*)&As[0][0] + awo0) = a0;
    *(uint4*)((char*)&As[0][0] + awo1) = a1;
    u32 pk[4];
    pk[0] = cvtpk(b0.x, b0.y); pk[1] = cvtpk(b0.z, b0.w);
    pk[2] = cvtpk(b1.x, b1.y); pk[3] = cvtpk(b1.z, b1.w);
    *(uint4*)((char*)&Bs[0][0] + bwo0) = *(uint4*)pk;
    pk[0] = cvtpk(b2.x, b2.y); pk[1] = cvtpk(b2.z, b2.w);
    pk[2] = cvtpk(b3.x, b3.y); pk[3] = cvtpk(b3.z, b3.w);
    *(uint4*)((char*)&Bs[0][0] + bwo1) = *(uint4*)pk;
  }
  LGKM0();
  SBAR();
  SCHED0();

  const int NS = kFF / 32;  // 128
  for (int s = 0; s < NS; s++) {
    const int cur = s & 1;
    const bool more = (s + 1 < NS);
    if (more) {  // issue next tile's loads early; they fly under the MFMA phase
      const u16* ap = agp + (s + 1) * 32;
      a0 = *(const uint4*)ap;
      a1 = *(const uint4*)(ap + 8);
      const float* bp = bgp + (s + 1) * 32;
      b0 = *(const float4*)bp;
      b1 = *(const float4*)(bp + 4);
      b2 = *(const float4*)(bp + 8);
      b3 = *(const float4*)(bp + 12);
    }
    SCHED0();
    const char* Ac = (const char*)&As[cur][0];
    const char* Bc = (const char*)&Bs[cur][0];
    bf16x8 af[4], bfr[4];
#pragma unroll
    for (int mi = 0; mi < 4; mi++) af[mi] = *(const bf16x8*)(Ac + aoff[mi]);
#pragma unroll
    for (int ni = 0; ni < 4; ni++) bfr[ni] = *(const bf16x8*)(Bc + boff[ni]);
#pragma unroll
    for (int mi = 0; mi < 4; mi++)
#pragma unroll
      for (int ni = 0; ni < 4; ni++) acc[mi][ni] = MFMA_BF16(af[mi], bfr[ni], acc[mi][ni]);
    if (more) {  // write next buffer (readers closed by previous barrier)
      char* Aw = (char*)&As[cur ^ 1][0];
      char* Bw = (char*)&Bs[cur ^ 1][0];
      *(uint4*)(Aw + awo0) = a0;
      *(uint4*)(Aw + awo1) = a1;
      u32 pk[4];
      pk[0] = cvtpk(b0.x, b0.y); pk[1] = cvtpk(b0.z, b0.w);
      pk[2] = cvtpk(b1.x, b1.y); pk[3] = cvtpk(b1.z, b1.w);
      *(uint4*)(Bw + bwo0) = *(uint4*)pk;
      pk[0] = cvtpk(b2.x, b2.y); pk[1] = cvtpk(b2.z, b2.w);
      pk[2] = cvtpk(b3.x, b3.y); pk[3] = cvtpk(b3.z, b3.w);
      *(uint4*)(Bw + bwo1) = *(uint4*)pk;
      LGKM0();
      SBAR();
      SCHED0();
    }
  }

#pragma unroll
  for (int mi = 0; mi < 4; mi++)
#pragma unroll
    for (int r = 0; r < 4; r++) {
      int ml = m0 + wr + mi * 16 + ((l >> 4) << 2) + r;
      if (ml >= Me) continue;
      size_t rb = (size_t)(base + ml) * kD;
#pragma unroll
      for (int ni = 0; ni < 4; ni++) {
        int col = n0 + wc + ni * 16 + (l & 15);
        eo[rb + col] = acc[mi][ni][r];
      }
    }
}

// ---------- final combine ----------
__global__ __launch_bounds__(256) void combine_kernel(
    const float* __restrict__ h, const float* __restrict__ eo,
    const float* __restrict__ gates, const int* __restrict__ slot_of,
    float* __restrict__ out) {
  const int s = blockIdx.x;
  const float g0 = gates[s * 2], g1 = gates[s * 2 + 1];
  const int p0 = slot_of[s * 2], p1 = slot_of[s * 2 + 1];
  const int c = threadIdx.x * 4;
  float4 hv = *(const float4*)(h + (size_t)s * kD + c);
  float4 e0 = *(const float4*)(eo + (size_t)p0 * kD + c);
  float4 e1 = *(const float4*)(eo + (size_t)p1 * kD + c);
  float4 o;
  o.x = hv.x + g0 * e0.x + g1 * e1.x;
  o.y = hv.y + g0 * e0.y + g1 * e1.y;
  o.z = hv.z + g0 * e0.z + g1 * e1.z;
  o.w = hv.w + g0 * e0.w + g1 * e1.w;
  *(float4*)(out + (size_t)s * kD + c) = o;
}

extern "C" void kernel_launch(void* const* d_in, const int* in_sizes, int n_in,
                              void* d_out, int out_size, void* d_ws, size_t ws_size,
                              hipStream_t stream) {
  (void)in_sizes; (void)n_in; (void)out_size; (void)ws_size;
  const float* x = (const float*)d_in[0];
  const float* scale_attn = (const float*)d_in[2];
  const float* Wq = (const float*)d_in[3];
  const float* Wk = (const float*)d_in[4];
  const float* Wv = (const float*)d_in[5];
  const float* Wo = (const float*)d_in[6];
  const float* scale_ffn = (const float*)d_in[7];
  const float* Wg = (const float*)d_in[8];
  const float* W_in = (const float*)d_in[9];
  const float* W_vv = (const float*)d_in[10];
  const float* W_out = (const float*)d_in[11];
  float* out = (float*)d_out;
  float* probs = out + (size_t)kS * kD;

  char* wsb = (char*)d_ws;
  size_t off = 0;
  auto alloc = [&](size_t bytes) -> void* {
    void* p = wsb + off;
    off += (bytes + 255) & ~(size_t)255;
    return p;
  };
  const size_t SDu = (size_t)kS * kD;
  u16* normA_dp = (u16*)alloc(SDu * 4);
  u32* qpk = (u32*)alloc(SDu * 4);
  u32* kpk = (u32*)alloc(SDu * 4);
  u32* vpk = (u32*)alloc(SDu * 4);
  u32* ctxpk = (u32*)alloc(SDu * 4);
  u16* Wqkv_dp = (u16*)alloc((size_t)3072 * 2048 * 2);
  u16* Wo_dp = (u16*)alloc((size_t)1024 * 2048 * 2);
  float* normFf = (float*)alloc(SDu * 4);
  float* eo = (float*)alloc((size_t)kSlotCap * kD * 4);
  float* h = (float*)alloc(SDu * 4);
  u16* normFb = (u16*)alloc(SDu * 2);
  u16* H = (u16*)alloc((size_t)kSlotCap * kFF * 2);
  float* Opart = (float*)alloc((size_t)2048 * 4096 * 4);
  float* mpart = (float*)alloc((size_t)2048 * 64 * 4);
  float* lpart = (float*)alloc((size_t)2048 * 64 * 4);
  float* gates = (float*)alloc(kS * 2 * 4);
  int* experts = (int*)alloc(kS * 2 * 4);
  int* slot_of = (int*)alloc(kS * 2 * 4);
  int* slot_list = (int*)alloc(kSlotCap * 4);
  int* counts = (int*)alloc(64);
  int* ebase = (int*)alloc(64);
  int* cursor = (int*)alloc(64);
  int2* tmap = (int2*)alloc(kMaxTiles * 8);

  pack_dp3<<<(3072 * 1024) / 256, 256, 0, stream>>>(Wq, Wk, Wv, Wqkv_dp);
  pack_dp1<<<(1024 * 1024) / 256, 256, 0, stream>>>(Wo, Wo_dp, 1024 * 1024);

  rmsnorm_kernel<0><<<kS, 256, 0, stream>>>(x, scale_attn, normA_dp, nullptr, nullptr);
  gemm_dp<0, 0><<<dim3(3072 / 128, kS / 128), 256, 0, stream>>>(
      normA_dp, Wqkv_dp, nullptr, kD, qpk, kpk, vpk, nullptr);
  attn_kernel<<<dim3(80, kH), 256, 0, stream>>>(qpk, kpk, vpk, Opart, mpart, lpart);
  attn_merge<<<dim3(kS / 64, kH), 256, 0, stream>>>(Opart, mpart, lpart, ctxpk);
  gemm_dp<1, 1><<<dim3(1024 / 128, kS / 128), 256, 0, stream>>>(
      ctxpk, Wo_dp, x, kD, nullptr, nullptr, nullptr, h);

  rmsnorm_kernel<1><<<kS, 256, 0, stream>>>(h, scale_ffn, nullptr, normFf, normFb);
  moe_init<<<1, 64, 0, stream>>>(counts);
  router_kernel<<<kS / 4, 256, 0, stream>>>(normFf, Wg, probs, gates, experts, counts);
  moe_scan<<<1, 64, 0, stream>>>(counts, ebase, cursor, tmap);
  moe_fill<<<kS / 256, 256, 0, stream>>>(experts, cursor, slot_list, slot_of);

  moe_mmA<<<dim3(8192 / 128, kMaxTiles), 256, 0, stream>>>(
      normFb, W_in, W_vv, slot_list, counts, ebase, tmap, H);
  moe_mm2<<<dim3(kD / 128, kMaxTiles), 256, 0, stream>>>(
      H, W_out, counts, ebase, tmap, eo);

  combine_kernel<<<kS, 256, 0, stream>>>(h, eo, gates, slot_of, out);
}

// Round 19
// 611.585 us; speedup vs baseline: 1.0416x; 1.0416x over previous
//
#include <hip/hip_runtime.h>
#include <hip/hip_bf16.h>
#include <math.h>

typedef unsigned int u32;
typedef unsigned short u16;
using bf16x8 = __attribute__((ext_vector_type(8))) short;
using f32x4 = __attribute__((ext_vector_type(4))) float;

#define MFMA_BF16(a, b, c) __builtin_amdgcn_mfma_f32_16x16x32_bf16((a), (b), (c), 0, 0, 0)
#define VMCNT8() asm volatile("s_waitcnt vmcnt(8)" ::: "memory")
#define VMCNT6() asm volatile("s_waitcnt vmcnt(6)" ::: "memory")
#define VMCNT0() asm volatile("s_waitcnt vmcnt(0)" ::: "memory")
#define LGKM0() asm volatile("s_waitcnt lgkmcnt(0)" ::: "memory")
#define SBAR() __builtin_amdgcn_s_barrier()
#define SCHED0() __builtin_amdgcn_sched_barrier(0)

constexpr int kS = 2048, kD = 1024, kH = 16, kE = 8, kFF = 4096;
constexpr int kSlotCap = 5120;  // 40 tiles x 128 (128-aligned expert bases)
constexpr int kMaxTiles = 40;
constexpr int kChunk = 8;       // kt tiles per attn block (512 tokens)

// ---------- numeric helpers ----------
__device__ __forceinline__ u16 bf16_rne(float f) {
  u32 u = __float_as_uint(f);
  u32 r = (u + 0x7fffu + ((u >> 16) & 1u)) >> 16;
  return (u16)r;
}
__device__ __forceinline__ float bf16_f32(u16 h) { return __uint_as_float(((u32)h) << 16); }
__device__ __forceinline__ u32 pack_hl(float x) {
  u16 hi = bf16_rne(x);
  u16 lo = bf16_rne(x - bf16_f32(hi));
  return ((u32)lo << 16) | (u32)hi;
}
__device__ __forceinline__ void unpack8(const u32* t, bf16x8& h, bf16x8& l) {
#pragma unroll
  for (int j = 0; j < 8; j++) {
    h[j] = (short)(t[j] & 0xffffu);
    l[j] = (short)(t[j] >> 16);
  }
}
__device__ __forceinline__ void gload_lds16(const void* g, void* l) {
  __builtin_amdgcn_global_load_lds((const __attribute__((address_space(1))) u32*)g,
                                   (__attribute__((address_space(3))) u32*)l, 16, 0, 0);
}
// packed f32x2 -> bf16x2 (RNE), single HW instruction
__device__ __forceinline__ u32 cvtpk(float a, float b) {
  u32 r;
  asm("v_cvt_pk_bf16_f32 %0, %1, %2" : "=v"(r) : "v"(a), "v"(b));
  return r;
}

// ---------- weight packs (attention path only) ----------
__global__ __launch_bounds__(256) void pack_dp3(const float* __restrict__ Wq,
                                                const float* __restrict__ Wk,
                                                const float* __restrict__ Wv,
                                                u16* __restrict__ o) {
  int i = blockIdx.x * 256 + threadIdx.x;
  if (i >= 3072 * 1024) return;
  int n = i >> 10, k = i & 1023;
  float v = (n < 1024) ? Wq[i] : (n < 2048) ? Wk[i - 1024 * 1024] : Wv[i - 2048 * 1024];
  u16 hi = bf16_rne(v);
  u16 lo = bf16_rne(v - bf16_f32(hi));
  size_t b = (size_t)n * 2048 + (size_t)(k >> 5) * 64 + (k & 31);
  o[b] = hi;
  o[b + 32] = lo;
}
__global__ __launch_bounds__(256) void pack_dp1(const float* __restrict__ W,
                                                u16* __restrict__ o, int n_elem) {
  int i = blockIdx.x * 256 + threadIdx.x;
  if (i >= n_elem) return;
  int k = i & 1023, n = i >> 10;
  float v = W[i];
  u16 hi = bf16_rne(v);
  u16 lo = bf16_rne(v - bf16_f32(hi));
  size_t b = (size_t)n * 2048 + (size_t)(k >> 5) * 64 + (k & 31);
  o[b] = hi;
  o[b + 32] = lo;
}

// ---------- RMSNorm. MODE 0: dual-plane u16. MODE 1: f32 + bf16 ----------
template <int MODE>
__global__ __launch_bounds__(256) void rmsnorm_kernel(
    const float* __restrict__ x, const float* __restrict__ scale,
    u16* __restrict__ odp, float* __restrict__ of32, u16* __restrict__ ob16) {
  const int s = blockIdx.x;
  const float* row = x + (size_t)s * kD;
  const int c = threadIdx.x * 4;
  float4 v = *(const float4*)(row + c);
  float ss = v.x * v.x + v.y * v.y + v.z * v.z + v.w * v.w;
#pragma unroll
  for (int m = 32; m; m >>= 1) ss += __shfl_xor(ss, m);
  __shared__ float wsum[4];
  if ((threadIdx.x & 63) == 0) wsum[threadIdx.x >> 6] = ss;
  __syncthreads();
  float tot = wsum[0] + wsum[1] + wsum[2] + wsum[3];
  float rinv = 1.0f / sqrtf(tot * (1.0f / kD) + 1e-5f);
  float4 sc = *(const float4*)(scale + c);
  float n[4] = {v.x * rinv * sc.x, v.y * rinv * sc.y, v.z * rinv * sc.z, v.w * rinv * sc.w};
  if (MODE == 0) {
    u16 hv[4], lv[4];
#pragma unroll
    for (int j = 0; j < 4; j++) {
      hv[j] = bf16_rne(n[j]);
      lv[j] = bf16_rne(n[j] - bf16_f32(hv[j]));
    }
    u16* o = odp + (size_t)s * 2048 + (size_t)(c >> 5) * 64 + (c & 31);
    *(uint2*)o = *(uint2*)hv;
    *(uint2*)(o + 32) = *(uint2*)lv;
  } else {
    *(float4*)(of32 + (size_t)s * kD + c) = make_float4(n[0], n[1], n[2], n[3]);
    u16* o = ob16 + (size_t)s * kD + c;
    o[0] = bf16_rne(n[0]); o[1] = bf16_rne(n[1]); o[2] = bf16_rne(n[2]); o[3] = bf16_rne(n[3]);
  }
}

// ---------- split-bf16 3-term GEMM (attention path), counted-vmcnt 2-phase ----------
template <int APK, int OUT>
__global__ __launch_bounds__(256) void gemm_dp(
    const void* __restrict__ Av, const u16* __restrict__ Bdp,
    const float* __restrict__ resid, int K,
    u32* __restrict__ oq, u32* __restrict__ ok, u32* __restrict__ ov,
    float* __restrict__ of) {
  __shared__ u16 As[2][128 * 64];
  __shared__ u16 Bs[2][128 * 64];
  const int tid = threadIdx.x, w = tid >> 6, l = tid & 63;
  const int m0 = blockIdx.y * 128, n0 = blockIdx.x * 128;
  const int wr = (w >> 1) * 64, wc = (w & 1) * 64;
  const char* Ab = (const char*)Av;
  const char* Bb = (const char*)Bdp;
  const size_t rowb = (size_t)K * 4;

  size_t asrc[4], bsrc[4];
  int dst[4];
#pragma unroll
  for (int i = 0; i < 4; i++) {
    int fl = i * 256 + tid;
    int row = fl >> 3, cb = fl & 7;
    size_t coff = (size_t)((cb ^ (row & 7)) * 16);
    asrc[i] = (size_t)(m0 + row) * rowb + coff;
    bsrc[i] = (size_t)(n0 + row) * rowb + coff;
    dst[i] = fl * 16;
  }

  f32x4 zero = {0.f, 0.f, 0.f, 0.f};
  f32x4 acc[4][4];
#pragma unroll
  for (int i = 0; i < 4; i++)
#pragma unroll
    for (int j = 0; j < 4; j++) acc[i][j] = zero;

  auto stage = [&](int buf, int s) {
    const char* ap = Ab + (size_t)s * 128;
    const char* bp = Bb + (size_t)s * 128;
#pragma unroll
    for (int i = 0; i < 4; i++) {
      gload_lds16(ap + asrc[i], (char*)&As[buf][0] + dst[i]);
      gload_lds16(bp + bsrc[i], (char*)&Bs[buf][0] + dst[i]);
    }
  };

  const int NS = K / 32;
  stage(0, 0);
  for (int s = 0; s < NS; s++) {
    const int cur = s & 1;
    const bool lastit = (s == NS - 1);
    if (!lastit) stage(cur ^ 1, s + 1);
    if (!lastit) VMCNT8(); else VMCNT0();
    SBAR();
    SCHED0();
    bf16x8 ah[4], al[4], bh[4], bl[4];
    const int g = l >> 4;
    if (APK) {
      const u32* At = (const u32*)&As[cur][0];
#pragma unroll
      for (int mi = 0; mi < 4; mi++) {
        int row = wr + mi * 16 + (l & 15);
        u32 t[8];
        *(uint4*)t = *(const uint4*)&At[row * 32 + (((2 * g) ^ (row & 7)) * 4)];
        *(uint4*)(t + 4) = *(const uint4*)&At[row * 32 + (((2 * g + 1) ^ (row & 7)) * 4)];
        unpack8(t, ah[mi], al[mi]);
      }
    } else {
#pragma unroll
      for (int mi = 0; mi < 4; mi++) {
        int row = wr + mi * 16 + (l & 15);
        ah[mi] = *(const bf16x8*)&As[cur][row * 64 + ((g ^ (row & 7)) * 8)];
        al[mi] = *(const bf16x8*)&As[cur][row * 64 + (((4 + g) ^ (row & 7)) * 8)];
      }
    }
#pragma unroll
    for (int ni = 0; ni < 4; ni++) {
      int row = wc + ni * 16 + (l & 15);
      bh[ni] = *(const bf16x8*)&Bs[cur][row * 64 + ((g ^ (row & 7)) * 8)];
      bl[ni] = *(const bf16x8*)&Bs[cur][row * 64 + (((4 + g) ^ (row & 7)) * 8)];
    }
#pragma unroll
    for (int mi = 0; mi < 4; mi++)
#pragma unroll
      for (int ni = 0; ni < 4; ni++) {
        f32x4 c = acc[mi][ni];
        c = MFMA_BF16(al[mi], bh[ni], c);
        c = MFMA_BF16(ah[mi], bl[ni], c);
        c = MFMA_BF16(ah[mi], bh[ni], c);
        acc[mi][ni] = c;
      }
    SCHED0();
    if (!lastit) SBAR();
  }

  if (OUT == 0) {
    u32* dstp;
    int nb;
    if (n0 < 1024) { dstp = oq; nb = n0; }
    else if (n0 < 2048) { dstp = ok; nb = n0 - 1024; }
    else { dstp = ov; nb = n0 - 2048; }
#pragma unroll
    for (int mi = 0; mi < 4; mi++)
#pragma unroll
      for (int ni = 0; ni < 4; ni++)
#pragma unroll
        for (int r = 0; r < 4; r++) {
          int row = m0 + wr + mi * 16 + ((l >> 4) << 2) + r;
          int col = nb + wc + ni * 16 + (l & 15);
          dstp[(size_t)row * 1024 + col] = pack_hl(acc[mi][ni][r]);
        }
  } else {
#pragma unroll
    for (int mi = 0; mi < 4; mi++)
#pragma unroll
      for (int ni = 0; ni < 4; ni++)
#pragma unroll
        for (int r = 0; r < 4; r++) {
          int row = m0 + wr + mi * 16 + ((l >> 4) << 2) + r;
          int col = n0 + wc + ni * 16 + (l & 15);
          of[(size_t)row * 1024 + col] = resid[(size_t)row * 1024 + col] + acc[mi][ni][r];
        }
  }
}

// ---------- flash attention, kt-chunked (validated round-6 version) ----------
__global__ __launch_bounds__(256) void attn_kernel(
    const u32* __restrict__ Qp, const u32* __restrict__ Kp, const u32* __restrict__ Vp,
    float* __restrict__ Opart, float* __restrict__ mpart, float* __restrict__ lpart) {
  constexpr int LDK = 68;
  __shared__ u32 Ks[64 * LDK];
  __shared__ u32 Vs[64 * LDK];
  __shared__ u32 Ps[64 * LDK];
  const int tid = threadIdx.x, w = tid >> 6, l = tid & 63;
  int b = blockIdx.x, qt, c;
  if (b < 8) { qt = b; c = 0; }
  else if (b < 24) { qt = 8 + ((b - 8) >> 1); c = (b - 8) & 1; }
  else if (b < 48) { qt = 16 + (b - 24) / 3; c = (b - 24) % 3; }
  else { qt = 24 + ((b - 48) >> 2); c = (b - 48) & 3; }
  const int hh = blockIdx.y;
  const int q0 = qt * 64, hc = hh * 64;
  const int kt0 = c * kChunk;
  const int kt1 = min(kt0 + kChunk, qt + 1);

  bf16x8 qh[2], ql[2];
  {
    const int qrow = q0 + w * 16 + (l & 15);
#pragma unroll
    for (int kk = 0; kk < 2; kk++) {
      u32 t[8];
      const u32* p = Qp + (size_t)qrow * kD + hc + kk * 32 + ((l >> 4) << 3);
      *(uint4*)t = *(const uint4*)p;
      *(uint4*)(t + 4) = *(const uint4*)(p + 4);
      unpack8(t, qh[kk], ql[kk]);
    }
  }
  float mrun[4], lrun[4];
  f32x4 zero = {0.f, 0.f, 0.f, 0.f};
  f32x4 oacc[4];
#pragma unroll
  for (int r = 0; r < 4; r++) { mrun[r] = -3.0e38f; lrun[r] = 0.f; }
#pragma unroll
  for (int vb = 0; vb < 4; vb++) oacc[vb] = zero;

  const int trow = tid >> 2, c0v = (tid & 3) * 16;
  const u32* gKb = Kp + hc + c0v;
  const u32* gVb = Vp + hc + c0v;
  uint4 kr[4], vr[4];
  {
    const u32* gK = gKb + (size_t)(kt0 * 64 + trow) * kD;
    kr[0] = *(const uint4*)gK; kr[1] = *(const uint4*)(gK + 4);
    kr[2] = *(const uint4*)(gK + 8); kr[3] = *(const uint4*)(gK + 12);
    const u32* gV = gVb + (size_t)(kt0 * 64 + trow) * kD;
    vr[0] = *(const uint4*)gV; vr[1] = *(const uint4*)(gV + 4);
    vr[2] = *(const uint4*)(gV + 8); vr[3] = *(const uint4*)(gV + 12);
  }

  for (int kt = kt0; kt < kt1; kt++) {
    {
      u32* sK = Ks + trow * LDK + c0v;
      *(uint4*)sK = kr[0]; *(uint4*)(sK + 4) = kr[1];
      *(uint4*)(sK + 8) = kr[2]; *(uint4*)(sK + 12) = kr[3];
#pragma unroll
      for (int j = 0; j < 4; j++) {
        Vs[(c0v + j * 4 + 0) * LDK + trow] = vr[j].x;
        Vs[(c0v + j * 4 + 1) * LDK + trow] = vr[j].y;
        Vs[(c0v + j * 4 + 2) * LDK + trow] = vr[j].z;
        Vs[(c0v + j * 4 + 3) * LDK + trow] = vr[j].w;
      }
    }
    __syncthreads();
    if (kt + 1 < kt1) {
      const u32* gK = gKb + (size_t)((kt + 1) * 64 + trow) * kD;
      kr[0] = *(const uint4*)gK; kr[1] = *(const uint4*)(gK + 4);
      kr[2] = *(const uint4*)(gK + 8); kr[3] = *(const uint4*)(gK + 12);
      const u32* gV = gVb + (size_t)((kt + 1) * 64 + trow) * kD;
      vr[0] = *(const uint4*)gV; vr[1] = *(const uint4*)(gV + 4);
      vr[2] = *(const uint4*)(gV + 8); vr[3] = *(const uint4*)(gV + 12);
    }

    f32x4 sfr[4];
#pragma unroll
    for (int kb = 0; kb < 4; kb++) {
      f32x4 sa = zero;
#pragma unroll
      for (int kk = 0; kk < 2; kk++) {
        u32 t[8];
        bf16x8 kh, kl;
        const u32* p = Ks + (kb * 16 + (l & 15)) * LDK + kk * 32 + ((l >> 4) << 3);
        *(uint4*)t = *(const uint4*)p;
        *(uint4*)(t + 4) = *(const uint4*)(p + 4);
        unpack8(t, kh, kl);
        sa = MFMA_BF16(ql[kk], kl, sa);
        sa = MFMA_BF16(ql[kk], kh, sa);
        sa = MFMA_BF16(qh[kk], kl, sa);
        sa = MFMA_BF16(qh[kk], kh, sa);
      }
      sfr[kb] = sa * 0.125f;
    }
    if (kt == qt) {
#pragma unroll
      for (int kb = 0; kb < 4; kb++) {
        int t = kt * 64 + kb * 16 + (l & 15);
#pragma unroll
        for (int r = 0; r < 4; r++) {
          int qq = q0 + w * 16 + ((l >> 4) << 2) + r;
          if (t > qq) sfr[kb][r] = -3.0e38f;
        }
      }
    }
#pragma unroll
    for (int r = 0; r < 4; r++) {
      float mx = fmaxf(fmaxf(sfr[0][r], sfr[1][r]), fmaxf(sfr[2][r], sfr[3][r]));
#pragma unroll
      for (int mm = 1; mm < 16; mm <<= 1) mx = fmaxf(mx, __shfl_xor(mx, mm));
      float mnew = fmaxf(mrun[r], mx);
      float sf = __expf(mrun[r] - mnew);
      mrun[r] = mnew;
      float rs = 0.f;
#pragma unroll
      for (int kb = 0; kb < 4; kb++) {
        float p = __expf(sfr[kb][r] - mnew);
        sfr[kb][r] = p;
        rs += p;
      }
#pragma unroll
      for (int mm = 1; mm < 16; mm <<= 1) rs += __shfl_xor(rs, mm);
      lrun[r] = lrun[r] * sf + rs;
#pragma unroll
      for (int vb = 0; vb < 4; vb++) oacc[vb][r] *= sf;
    }
#pragma unroll
    for (int kb = 0; kb < 4; kb++)
#pragma unroll
      for (int r = 0; r < 4; r++)
        Ps[(w * 16 + ((l >> 4) << 2) + r) * LDK + kb * 16 + (l & 15)] = pack_hl(sfr[kb][r]);
#pragma unroll
    for (int ks = 0; ks < 2; ks++) {
      bf16x8 ph, pl;
      {
        u32 t[8];
        const u32* pp = Ps + (w * 16 + (l & 15)) * LDK + ks * 32 + ((l >> 4) << 3);
        *(uint4*)t = *(const uint4*)pp;
        *(uint4*)(t + 4) = *(const uint4*)(pp + 4);
        unpack8(t, ph, pl);
      }
#pragma unroll
      for (int vb = 0; vb < 4; vb++) {
        u32 t2[8];
        bf16x8 vh, vl;
        const u32* pv = Vs + (vb * 16 + (l & 15)) * LDK + ks * 32 + ((l >> 4) << 3);
        *(uint4*)t2 = *(const uint4*)pv;
        *(uint4*)(t2 + 4) = *(const uint4*)(pv + 4);
        unpack8(t2, vh, vl);
        f32x4 cc = oacc[vb];
        cc = MFMA_BF16(pl, vl, cc);
        cc = MFMA_BF16(pl, vh, cc);
        cc = MFMA_BF16(ph, vl, cc);
        cc = MFMA_BF16(ph, vh, cc);
        oacc[vb] = cc;
      }
    }
    __syncthreads();
  }

  const int p = (qt * 16 + hh) * 4 + c;
  float* Po = Opart + (size_t)p * 4096;
#pragma unroll
  for (int vb = 0; vb < 4; vb++)
#pragma unroll
    for (int r = 0; r < 4; r++) {
      int rl = w * 16 + ((l >> 4) << 2) + r;
      int cl = vb * 16 + (l & 15);
      Po[rl * 64 + cl] = oacc[vb][r];
    }
  if ((l & 15) == 0) {
#pragma unroll
    for (int r = 0; r < 4; r++) {
      int rl = w * 16 + ((l >> 4) << 2) + r;
      mpart[p * 64 + rl] = mrun[r];
      lpart[p * 64 + rl] = lrun[r];
    }
  }
}

// ---------- merge chunk partials -> packed ctx ----------
__global__ __launch_bounds__(256) void attn_merge(
    const float* __restrict__ Opart, const float* __restrict__ mpart,
    const float* __restrict__ lpart, u32* __restrict__ Op) {
  const int qt = blockIdx.x, hh = blockIdx.y;
  const int nch = (qt + kChunk) >> 3;
  const int t = threadIdx.x;
  const int row = t >> 2;
  const int c0 = (t & 3) * 16;
  const int pbase = (qt * 16 + hh) * 4;
  float M = -3.0e38f;
  for (int c = 0; c < nch; c++) M = fmaxf(M, mpart[(pbase + c) * 64 + row]);
  float den = 0.f;
  float acc[16];
#pragma unroll
  for (int j = 0; j < 16; j++) acc[j] = 0.f;
  for (int c = 0; c < nch; c++) {
    float wgt = __expf(mpart[(pbase + c) * 64 + row] - M);
    den += wgt * lpart[(pbase + c) * 64 + row];
    const float* po = Opart + (size_t)(pbase + c) * 4096 + row * 64 + c0;
#pragma unroll
    for (int j = 0; j < 16; j += 4) {
      float4 v = *(const float4*)(po + j);
      acc[j] += wgt * v.x; acc[j + 1] += wgt * v.y;
      acc[j + 2] += wgt * v.z; acc[j + 3] += wgt * v.w;
    }
  }
  float inv = 1.f / den;
  u32* dst = Op + (size_t)(qt * 64 + row) * kD + hh * 64 + c0;
#pragma unroll
  for (int j = 0; j < 16; j++) dst[j] = pack_hl(acc[j] * inv);
}

// ---------- router ----------
__global__ __launch_bounds__(256) void router_kernel(
    const float* __restrict__ normed, const float* __restrict__ Wg,
    float* __restrict__ probs, float* __restrict__ gates,
    int* __restrict__ experts, int* __restrict__ counts) {
  const int w = threadIdx.x >> 6, l = threadIdx.x & 63;
  const int s = blockIdx.x * 4 + w;
  float lg[kE];
  const float* row = normed + (size_t)s * kD;
#pragma unroll
  for (int e = 0; e < kE; e++) {
    const float* wg = Wg + (size_t)e * kD;
    float a = 0.f;
    for (int d = l; d < kD; d += 64) a += row[d] * wg[d];
#pragma unroll
    for (int m = 32; m; m >>= 1) a += __shfl_xor(a, m);
    lg[e] = a;
  }
  if (l == 0) {
    float mx = lg[0];
#pragma unroll
    for (int e = 1; e < kE; e++) mx = fmaxf(mx, lg[e]);
    float p[kE], sum = 0.f;
#pragma unroll
    for (int e = 0; e < kE; e++) { p[e] = __expf(lg[e] - mx); sum += p[e]; }
    float inv = 1.f / sum;
#pragma unroll
    for (int e = 0; e < kE; e++) { p[e] *= inv; probs[(size_t)s * kE + e] = p[e]; }
    int i1 = 0;
#pragma unroll
    for (int e = 1; e < kE; e++) if (lg[e] > lg[i1]) i1 = e;
    int i2 = (i1 == 0) ? 1 : 0;
#pragma unroll
    for (int e = 0; e < kE; e++) if (e != i1 && lg[e] > lg[i2]) i2 = e;
    float den = 1.f / (p[i1] + p[i2]);
    gates[s * 2] = p[i1] * den;
    gates[s * 2 + 1] = p[i2] * den;
    experts[s * 2] = i1;
    experts[s * 2 + 1] = i2;
    atomicAdd(&counts[i1], 1);
    atomicAdd(&counts[i2], 1);
  }
}

__global__ void moe_init(int* counts) {
  if (threadIdx.x < kE) counts[threadIdx.x] = 0;
}
__global__ void moe_scan(const int* __restrict__ counts, int* __restrict__ ebase,
                         int* __restrict__ cursor, int2* __restrict__ tmap) {
  if (threadIdx.x == 0) {
    int acc = 0, t = 0;
    for (int e = 0; e < kE; e++) {
      ebase[e] = acc;
      cursor[e] = acc;
      int nt = (counts[e] + 127) >> 7;
      for (int i = 0; i < nt; i++) tmap[t++] = make_int2(e, i * 128);
      acc += nt << 7;
    }
    ebase[kE] = acc;
    for (; t < kMaxTiles; t++) tmap[t] = make_int2(-1, 0);
  }
}
__global__ void moe_fill(const int* __restrict__ experts, int* __restrict__ cursor,
                         int* __restrict__ slot_list, int* __restrict__ slot_of) {
  int s = blockIdx.x * 256 + threadIdx.x;
  if (s >= kS) return;
  for (int k = 0; k < 2; k++) {
    int e = experts[s * 2 + k];
    int pos = atomicAdd(&cursor[e], 1);
    slot_list[pos] = s;
    slot_of[s * 2 + k] = pos;
  }
}

// ---------- MoE GEMM A: fused gelu, f32 weights DIRECT, BK=32 (round-17 validated) ----------
__global__ __launch_bounds__(256) void moe_mmA(
    const u16* __restrict__ A, const float* __restrict__ Wi, const float* __restrict__ Wv2,
    const int* __restrict__ slot_list, const int* __restrict__ counts,
    const int* __restrict__ ebase, const int2* __restrict__ tmap,
    u16* __restrict__ H) {
  int2 tm = tmap[blockIdx.y];
  const int e = tm.x;
  if (e < 0) return;
  const int base = ebase[e], Me = counts[e], m0 = tm.y;
  const int n0 = blockIdx.x * 128;  // interleaved col base (0..8191)
  __shared__ u16 As[2][64 * 64];    // 8 KB per buffer
  __shared__ float Bsf[2][128 * 32];  // 16 KB per buffer
  const int tid = threadIdx.x, w = tid >> 6, l = tid & 63;
  const int wr = (w >> 1) * 64, wc = (w & 1) * 64;
  const char* Ab = (const char*)A;

  size_t asrc[2];
  int adst[2];
#pragma unroll
  for (int i = 0; i < 2; i++) {
    int fl = i * 256 + tid;
    int lrow = fl >> 3, sl = fl & 7;
    int sp = sl ^ (lrow & 7);
    int t = 2 * lrow + (sp >> 2);
    int cbl = sp & 3;
    int mr = m0 + t;
    if (mr > Me - 1) mr = Me - 1;
    int ar = slot_list[base + mr];
    asrc[i] = (size_t)ar * 2048 + (size_t)cbl * 16;
    adst[i] = fl * 16;
  }
  const char* bptr[4];
  int bdst[4];
#pragma unroll
  for (int i = 0; i < 4; i++) {
    int fl = i * 256 + tid;
    int row = fl >> 3, sl = fl & 7;
    int sp = sl ^ (row & 7);
    int nn = n0 + row;
    const float* srcT = (nn & 1) ? Wv2 : Wi;
    bptr[i] = (const char*)(srcT + ((size_t)e * 4096 + (nn >> 1)) * 1024) + sp * 16;
    bdst[i] = fl * 16;
  }

  const int g = l >> 4;
  int aoff[4], boff0[4], boff1[4];
#pragma unroll
  for (int mi = 0; mi < 4; mi++) {
    int t = wr + mi * 16 + (l & 15);
    int lr = t >> 1;
    int sl = (((t & 1) << 2) | g) ^ (lr & 7);
    aoff[mi] = lr * 128 + sl * 16;
  }
#pragma unroll
  for (int ni = 0; ni < 4; ni++) {
    int rr = wc + ni * 16 + (l & 15);
    boff0[ni] = rr * 128 + (((2 * g) ^ (rr & 7)) * 16);
    boff1[ni] = rr * 128 + (((2 * g + 1) ^ (rr & 7)) * 16);
  }

  f32x4 zero = {0.f, 0.f, 0.f, 0.f};
  f32x4 acc[4][4];
#pragma unroll
  for (int i = 0; i < 4; i++)
#pragma unroll
    for (int j = 0; j < 4; j++) acc[i][j] = zero;

  auto stage = [&](int buf, int s) {
    const size_t soA = (size_t)s * 64;
    const size_t soB = (size_t)s * 128;
#pragma unroll
    for (int i = 0; i < 2; i++)
      gload_lds16(Ab + soA + asrc[i], (char*)&As[buf][0] + adst[i]);
#pragma unroll
    for (int i = 0; i < 4; i++)
      gload_lds16(bptr[i] + soB, (char*)&Bsf[buf][0] + bdst[i]);
  };

  const int NS = kD / 32;  // 32
  stage(0, 0);
  for (int s = 0; s < NS; s++) {
    const int cur = s & 1;
    const bool lastit = (s == NS - 1);
    if (!lastit) stage(cur ^ 1, s + 1);
    if (!lastit) VMCNT6(); else VMCNT0();
    SBAR();
    SCHED0();
    const char* Ac = (const char*)&As[cur][0];
    const char* Bc = (const char*)&Bsf[cur][0];
    bf16x8 af[4], bfr[4];
#pragma unroll
    for (int mi = 0; mi < 4; mi++) af[mi] = *(const bf16x8*)(Ac + aoff[mi]);
#pragma unroll
    for (int ni = 0; ni < 4; ni++) {
      float4 f0 = *(const float4*)(Bc + boff0[ni]);
      float4 f1 = *(const float4*)(Bc + boff1[ni]);
      u32 pk[4];
      pk[0] = cvtpk(f0.x, f0.y);
      pk[1] = cvtpk(f0.z, f0.w);
      pk[2] = cvtpk(f1.x, f1.y);
      pk[3] = cvtpk(f1.z, f1.w);
      bfr[ni] = *(bf16x8*)pk;
    }
#pragma unroll
    for (int mi = 0; mi < 4; mi++)
#pragma unroll
      for (int ni = 0; ni < 4; ni++) acc[mi][ni] = MFMA_BF16(af[mi], bfr[ni], acc[mi][ni]);
    SCHED0();
    if (!lastit) SBAR();
  }

#pragma unroll
  for (int mi = 0; mi < 4; mi++)
#pragma unroll
    for (int r = 0; r < 4; r++) {
      int ml = m0 + wr + mi * 16 + ((l >> 4) << 2) + r;
      if (ml >= Me) continue;
      size_t rb = (size_t)(base + ml) * 4096;
#pragma unroll
      for (int ni = 0; ni < 4; ni++) {
        int col = n0 + wc + ni * 16 + (l & 15);
        float v0 = acc[mi][ni][r];
        float pv = __shfl_xor(v0, 1);
        if ((l & 1) == 0) {
          float ge = 0.5f * v0 * (1.0f + erff(v0 * 0.70710678118654752f));
          H[rb + (col >> 1)] = bf16_rne(ge * pv);
        }
      }
    }
}

// ---------- MoE GEMM 2: N=64, reg-staged single-barrier pipeline (round-14/15/17 validated) ----------
__global__ __launch_bounds__(256) void moe_mm2(
    const u16* __restrict__ H, const float* __restrict__ Wo_f,
    const int* __restrict__ counts, const int* __restrict__ ebase,
    const int2* __restrict__ tmap, float* __restrict__ eo) {
  int2 tm = tmap[blockIdx.y];
  const int e = tm.x;
  if (e < 0) return;
  const int base = ebase[e], Me = counts[e], m0 = tm.y;
  const int n0 = blockIdx.x * 64;
  __shared__ u16 As[2][64 * 64];  // 8 KB per buffer (128 tile rows paired)
  __shared__ u16 Bs[2][32 * 64];  // 4 KB per buffer (64 tile rows paired)
  const int tid = threadIdx.x, w = tid >> 6, l = tid & 63;
  const int wr = (w >> 1) * 64, wc = (w & 1) * 32;

  const int srow = tid >> 1, sh = tid & 1;
  int mrA = m0 + srow;
  if (mrA > Me - 1) mrA = Me - 1;
  const u16* agp = H + (size_t)(base + mrA) * 4096 + sh * 16;  // +s*32 per step
  const int wlA = srow >> 1;
  const int awo0 = wlA * 128 + (((((srow & 1) << 2) | (sh * 2)) ^ (wlA & 7)) * 16);
  const int awo1 = wlA * 128 + (((((srow & 1) << 2) | (sh * 2 + 1)) ^ (wlA & 7)) * 16);
  const int brow = tid >> 2, bq = tid & 3;
  const float* bgp = Wo_f + ((size_t)e * 1024 + n0 + brow) * 4096 + bq * 8;  // +s*32
  const int wlB = brow >> 1;
  const int bwo = wlB * 128 + (((((brow & 1) << 2) | bq) ^ (wlB & 7)) * 16);

  const int g = l >> 4;
  int aoff[4], boff[2];
#pragma unroll
  for (int mi = 0; mi < 4; mi++) {
    int t = wr + mi * 16 + (l & 15);
    int lr = t >> 1;
    aoff[mi] = lr * 128 + (((((t & 1) << 2) | g) ^ (lr & 7)) * 16);
  }
#pragma unroll
  for (int ni = 0; ni < 2; ni++) {
    int t = wc + ni * 16 + (l & 15);
    int lr = t >> 1;
    boff[ni] = lr * 128 + (((((t & 1) << 2) | g) ^ (lr & 7)) * 16);
  }

  f32x4 zero = {0.f, 0.f, 0.f, 0.f};
  f32x4 acc[4][2];
#pragma unroll
  for (int i = 0; i < 4; i++)
#pragma unroll
    for (int j = 0; j < 2; j++) acc[i][j] = zero;

  // prologue: stage step 0 into buf 0
  uint4 a0 = *(const uint4*)agp;
  uint4 a1 = *(const uint4*)(agp + 8);
  float4 b0 = *(const float4*)bgp;
  float4 b1 = *(const float4*)(bgp + 4);
  {
    *(uint4*)((char*)&As[0][0] + awo0) = a0;
    *(uint4*)((char*)&As[0][0] + awo1) = a1;
    u32 pk[4];
    pk[0] = cvtpk(b0.x, b0.y); pk[1] = cvtpk(b0.z, b0.w);
    pk[2] = cvtpk(b1.x, b1.y); pk[3] = cvtpk(b1.z, b1.w);
    *(uint4*)((char*)&Bs[0][0] + bwo) = *(uint4*)pk;
  }
  LGKM0();
  SBAR();
  SCHED0();

  const int NS = kFF / 32;  // 128
  for (int s = 0; s < NS; s++) {
    const int cur = s & 1;
    const bool more = (s + 1 < NS);
    if (more) {
      const u16* ap = agp + (s + 1) * 32;
      a0 = *(const uint4*)ap;
      a1 = *(const uint4*)(ap + 8);
      const float* bp = bgp + (s + 1) * 32;
      b0 = *(const float4*)bp;
      b1 = *(const float4*)(bp + 4);
    }
    SCHED0();
    const char* Ac = (const char*)&As[cur][0];
    const char* Bc = (const char*)&Bs[cur][0];
    bf16x8 af[4], bfr[2];
#pragma unroll
    for (int mi = 0; mi < 4; mi++) af[mi] = *(const bf16x8*)(Ac + aoff[mi]);
#pragma unroll
    for (int ni = 0; ni < 2; ni++) bfr[ni] = *(const bf16x8*)(Bc + boff[ni]);
#pragma unroll
    for (int mi = 0; mi < 4; mi++)
#pragma unroll
      for (int ni = 0; ni < 2; ni++) acc[mi][ni] = MFMA_BF16(af[mi], bfr[ni], acc[mi][ni]);
    if (more) {
      char* Aw = (char*)&As[cur ^ 1][0];
      char* Bw = (char*)&Bs[cur ^ 1][0];
      *(uint4*)(Aw + awo0) = a0;
      *(uint4*)(Aw + awo1) = a1;
      u32 pk[4];
      pk[0] = cvtpk(b0.x, b0.y); pk[1] = cvtpk(b0.z, b0.w);
      pk[2] = cvtpk(b1.x, b1.y); pk[3] = cvtpk(b1.z, b1.w);
      *(uint4*)(Bw + bwo) = *(uint4*)pk;
      LGKM0();
      SBAR();
      SCHED0();
    }
  }

#pragma unroll
  for (int mi = 0; mi < 4; mi++)
#pragma unroll
    for (int r = 0; r < 4; r++) {
      int ml = m0 + wr + mi * 16 + ((l >> 4) << 2) + r;
      if (ml >= Me) continue;
      size_t rb = (size_t)(base + ml) * kD;
#pragma unroll
      for (int ni = 0; ni < 2; ni++) {
        int col = n0 + wc + ni * 16 + (l & 15);
        eo[rb + col] = acc[mi][ni][r];
      }
    }
}

// ---------- final combine ----------
__global__ __launch_bounds__(256) void combine_kernel(
    const float* __restrict__ h, const float* __restrict__ eo,
    const float* __restrict__ gates, const int* __restrict__ slot_of,
    float* __restrict__ out) {
  const int s = blockIdx.x;
  const float g0 = gates[s * 2], g1 = gates[s * 2 + 1];
  const int p0 = slot_of[s * 2], p1 = slot_of[s * 2 + 1];
  const int c = threadIdx.x * 4;
  float4 hv = *(const float4*)(h + (size_t)s * kD + c);
  float4 e0 = *(const float4*)(eo + (size_t)p0 * kD + c);
  float4 e1 = *(const float4*)(eo + (size_t)p1 * kD + c);
  float4 o;
  o.x = hv.x + g0 * e0.x + g1 * e1.x;
  o.y = hv.y + g0 * e0.y + g1 * e1.y;
  o.z = hv.z + g0 * e0.z + g1 * e1.z;
  o.w = hv.w + g0 * e0.w + g1 * e1.w;
  *(float4*)(out + (size_t)s * kD + c) = o;
}

extern "C" void kernel_launch(void* const* d_in, const int* in_sizes, int n_in,
                              void* d_out, int out_size, void* d_ws, size_t ws_size,
                              hipStream_t stream) {
  (void)in_sizes; (void)n_in; (void)out_size; (void)ws_size;
  const float* x = (const float*)d_in[0];
  const float* scale_attn = (const float*)d_in[2];
  const float* Wq = (const float*)d_in[3];
  const float* Wk = (const float*)d_in[4];
  const float* Wv = (const float*)d_in[5];
  const float* Wo = (const float*)d_in[6];
  const float* scale_ffn = (const float*)d_in[7];
  const float* Wg = (const float*)d_in[8];
  const float* W_in = (const float*)d_in[9];
  const float* W_vv = (const float*)d_in[10];
  const float* W_out = (const float*)d_in[11];
  float* out = (float*)d_out;
  float* probs = out + (size_t)kS * kD;

  char* wsb = (char*)d_ws;
  size_t off = 0;
  auto alloc = [&](size_t bytes) -> void* {
    void* p = wsb + off;
    off += (bytes + 255) & ~(size_t)255;
    return p;
  };
  const size_t SDu = (size_t)kS * kD;
  u16* normA_dp = (u16*)alloc(SDu * 4);
  u32* qpk = (u32*)alloc(SDu * 4);
  u32* kpk = (u32*)alloc(SDu * 4);
  u32* vpk = (u32*)alloc(SDu * 4);
  u32* ctxpk = (u32*)alloc(SDu * 4);
  u16* Wqkv_dp = (u16*)alloc((size_t)3072 * 2048 * 2);
  u16* Wo_dp = (u16*)alloc((size_t)1024 * 2048 * 2);
  float* normFf = (float*)alloc(SDu * 4);
  float* eo = (float*)alloc((size_t)kSlotCap * kD * 4);
  float* h = (float*)alloc(SDu * 4);
  u16* normFb = (u16*)alloc(SDu * 2);
  u16* H = (u16*)alloc((size_t)kSlotCap * kFF * 2);
  float* Opart = (float*)alloc((size_t)2048 * 4096 * 4);
  float* mpart = (float*)alloc((size_t)2048 * 64 * 4);
  float* lpart = (float*)alloc((size_t)2048 * 64 * 4);
  float* gates = (float*)alloc(kS * 2 * 4);
  int* experts = (int*)alloc(kS * 2 * 4);
  int* slot_of = (int*)alloc(kS * 2 * 4);
  int* slot_list = (int*)alloc(kSlotCap * 4);
  int* counts = (int*)alloc(64);
  int* ebase = (int*)alloc(64);
  int* cursor = (int*)alloc(64);
  int2* tmap = (int2*)alloc(kMaxTiles * 8);

  pack_dp3<<<(3072 * 1024) / 256, 256, 0, stream>>>(Wq, Wk, Wv, Wqkv_dp);
  pack_dp1<<<(1024 * 1024) / 256, 256, 0, stream>>>(Wo, Wo_dp, 1024 * 1024);

  rmsnorm_kernel<0><<<kS, 256, 0, stream>>>(x, scale_attn, normA_dp, nullptr, nullptr);
  gemm_dp<0, 0><<<dim3(3072 / 128, kS / 128), 256, 0, stream>>>(
      normA_dp, Wqkv_dp, nullptr, kD, qpk, kpk, vpk, nullptr);
  attn_kernel<<<dim3(80, kH), 256, 0, stream>>>(qpk, kpk, vpk, Opart, mpart, lpart);
  attn_merge<<<dim3(kS / 64, kH), 256, 0, stream>>>(Opart, mpart, lpart, ctxpk);
  gemm_dp<1, 1><<<dim3(1024 / 128, kS / 128), 256, 0, stream>>>(
      ctxpk, Wo_dp, x, kD, nullptr, nullptr, nullptr, h);

  rmsnorm_kernel<1><<<kS, 256, 0, stream>>>(h, scale_ffn, nullptr, normFf, normFb);
  moe_init<<<1, 64, 0, stream>>>(counts);
  router_kernel<<<kS / 4, 256, 0, stream>>>(normFf, Wg, probs, gates, experts, counts);
  moe_scan<<<1, 64, 0, stream>>>(counts, ebase, cursor, tmap);
  moe_fill<<<kS / 256, 256, 0, stream>>>(experts, cursor, slot_list, slot_of);

  moe_mmA<<<dim3(8192 / 128, kMaxTiles), 256, 0, stream>>>(
      normFb, W_in, W_vv, slot_list, counts, ebase, tmap, H);
  moe_mm2<<<dim3(kD / 64, kMaxTiles), 256, 0, stream>>>(
      H, W_out, counts, ebase, tmap, eo);

  combine_kernel<<<kS, 256, 0, stream>>>(h, eo, gates, slot_of, out);
}

// Round 20
// 602.708 us; speedup vs baseline: 1.0570x; 1.0147x over previous
//
#include <hip/hip_runtime.h>
#include <hip/hip_bf16.h>
#include <math.h>

typedef unsigned int u32;
typedef unsigned short u16;
using bf16x8 = __attribute__((ext_vector_type(8))) short;
using f32x4 = __attribute__((ext_vector_type(4))) float;

#define MFMA_BF16(a, b, c) __builtin_amdgcn_mfma_f32_16x16x32_bf16((a), (b), (c), 0, 0, 0)
#define VMCNT8() asm volatile("s_waitcnt vmcnt(8)" ::: "memory")
#define VMCNT6() asm volatile("s_waitcnt vmcnt(6)" ::: "memory")
#define VMCNT0() asm volatile("s_waitcnt vmcnt(0)" ::: "memory")
#define LGKM0() asm volatile("s_waitcnt lgkmcnt(0)" ::: "memory")
#define SBAR() __builtin_amdgcn_s_barrier()
#define SCHED0() __builtin_amdgcn_sched_barrier(0)

constexpr int kS = 2048, kD = 1024, kH = 16, kE = 8, kFF = 4096;
constexpr int kSlotCap = 5120;  // 40 tiles x 128 (128-aligned expert bases)
constexpr int kMaxTiles = 40;
constexpr int kChunk = 8;       // kt tiles per attn block (512 tokens)

// ---------- numeric helpers ----------
__device__ __forceinline__ u16 bf16_rne(float f) {
  u32 u = __float_as_uint(f);
  u32 r = (u + 0x7fffu + ((u >> 16) & 1u)) >> 16;
  return (u16)r;
}
__device__ __forceinline__ float bf16_f32(u16 h) { return __uint_as_float(((u32)h) << 16); }
__device__ __forceinline__ u32 pack_hl(float x) {
  u16 hi = bf16_rne(x);
  u16 lo = bf16_rne(x - bf16_f32(hi));
  return ((u32)lo << 16) | (u32)hi;
}
__device__ __forceinline__ void unpack8(const u32* t, bf16x8& h, bf16x8& l) {
#pragma unroll
  for (int j = 0; j < 8; j++) {
    h[j] = (short)(t[j] & 0xffffu);
    l[j] = (short)(t[j] >> 16);
  }
}
__device__ __forceinline__ void gload_lds16(const void* g, void* l) {
  __builtin_amdgcn_global_load_lds((const __attribute__((address_space(1))) u32*)g,
                                   (__attribute__((address_space(3))) u32*)l, 16, 0, 0);
}
// packed f32x2 -> bf16x2 (RNE), single HW instruction
__device__ __forceinline__ u32 cvtpk(float a, float b) {
  u32 r;
  asm("v_cvt_pk_bf16_f32 %0, %1, %2" : "=v"(r) : "v"(a), "v"(b));
  return r;
}

// ---------- weight packs (attention path only) ----------
__global__ __launch_bounds__(256) void pack_dp3(const float* __restrict__ Wq,
                                                const float* __restrict__ Wk,
                                                const float* __restrict__ Wv,
                                                u16* __restrict__ o) {
  int i = blockIdx.x * 256 + threadIdx.x;
  if (i >= 3072 * 1024) return;
  int n = i >> 10, k = i & 1023;
  float v = (n < 1024) ? Wq[i] : (n < 2048) ? Wk[i - 1024 * 1024] : Wv[i - 2048 * 1024];
  u16 hi = bf16_rne(v);
  u16 lo = bf16_rne(v - bf16_f32(hi));
  size_t b = (size_t)n * 2048 + (size_t)(k >> 5) * 64 + (k & 31);
  o[b] = hi;
  o[b + 32] = lo;
}
__global__ __launch_bounds__(256) void pack_dp1(const float* __restrict__ W,
                                                u16* __restrict__ o, int n_elem) {
  int i = blockIdx.x * 256 + threadIdx.x;
  if (i >= n_elem) return;
  int k = i & 1023, n = i >> 10;
  float v = W[i];
  u16 hi = bf16_rne(v);
  u16 lo = bf16_rne(v - bf16_f32(hi));
  size_t b = (size_t)n * 2048 + (size_t)(k >> 5) * 64 + (k & 31);
  o[b] = hi;
  o[b + 32] = lo;
}

// ---------- RMSNorm. MODE 0: dual-plane u16. MODE 1: f32 + bf16 ----------
template <int MODE>
__global__ __launch_bounds__(256) void rmsnorm_kernel(
    const float* __restrict__ x, const float* __restrict__ scale,
    u16* __restrict__ odp, float* __restrict__ of32, u16* __restrict__ ob16) {
  const int s = blockIdx.x;
  const float* row = x + (size_t)s * kD;
  const int c = threadIdx.x * 4;
  float4 v = *(const float4*)(row + c);
  float ss = v.x * v.x + v.y * v.y + v.z * v.z + v.w * v.w;
#pragma unroll
  for (int m = 32; m; m >>= 1) ss += __shfl_xor(ss, m);
  __shared__ float wsum[4];
  if ((threadIdx.x & 63) == 0) wsum[threadIdx.x >> 6] = ss;
  __syncthreads();
  float tot = wsum[0] + wsum[1] + wsum[2] + wsum[3];
  float rinv = 1.0f / sqrtf(tot * (1.0f / kD) + 1e-5f);
  float4 sc = *(const float4*)(scale + c);
  float n[4] = {v.x * rinv * sc.x, v.y * rinv * sc.y, v.z * rinv * sc.z, v.w * rinv * sc.w};
  if (MODE == 0) {
    u16 hv[4], lv[4];
#pragma unroll
    for (int j = 0; j < 4; j++) {
      hv[j] = bf16_rne(n[j]);
      lv[j] = bf16_rne(n[j] - bf16_f32(hv[j]));
    }
    u16* o = odp + (size_t)s * 2048 + (size_t)(c >> 5) * 64 + (c & 31);
    *(uint2*)o = *(uint2*)hv;
    *(uint2*)(o + 32) = *(uint2*)lv;
  } else {
    *(float4*)(of32 + (size_t)s * kD + c) = make_float4(n[0], n[1], n[2], n[3]);
    u16* o = ob16 + (size_t)s * kD + c;
    o[0] = bf16_rne(n[0]); o[1] = bf16_rne(n[1]); o[2] = bf16_rne(n[2]); o[3] = bf16_rne(n[3]);
  }
}

// ---------- split-bf16 3-term GEMM (attention path), counted-vmcnt 2-phase ----------
template <int APK, int OUT>
__global__ __launch_bounds__(256) void gemm_dp(
    const void* __restrict__ Av, const u16* __restrict__ Bdp,
    const float* __restrict__ resid, int K,
    u32* __restrict__ oq, u32* __restrict__ ok, u32* __restrict__ ov,
    float* __restrict__ of) {
  __shared__ u16 As[2][128 * 64];
  __shared__ u16 Bs[2][128 * 64];
  const int tid = threadIdx.x, w = tid >> 6, l = tid & 63;
  const int m0 = blockIdx.y * 128, n0 = blockIdx.x * 128;
  const int wr = (w >> 1) * 64, wc = (w & 1) * 64;
  const char* Ab = (const char*)Av;
  const char* Bb = (const char*)Bdp;
  const size_t rowb = (size_t)K * 4;

  size_t asrc[4], bsrc[4];
  int dst[4];
#pragma unroll
  for (int i = 0; i < 4; i++) {
    int fl = i * 256 + tid;
    int row = fl >> 3, cb = fl & 7;
    size_t coff = (size_t)((cb ^ (row & 7)) * 16);
    asrc[i] = (size_t)(m0 + row) * rowb + coff;
    bsrc[i] = (size_t)(n0 + row) * rowb + coff;
    dst[i] = fl * 16;
  }

  f32x4 zero = {0.f, 0.f, 0.f, 0.f};
  f32x4 acc[4][4];
#pragma unroll
  for (int i = 0; i < 4; i++)
#pragma unroll
    for (int j = 0; j < 4; j++) acc[i][j] = zero;

  auto stage = [&](int buf, int s) {
    const char* ap = Ab + (size_t)s * 128;
    const char* bp = Bb + (size_t)s * 128;
#pragma unroll
    for (int i = 0; i < 4; i++) {
      gload_lds16(ap + asrc[i], (char*)&As[buf][0] + dst[i]);
      gload_lds16(bp + bsrc[i], (char*)&Bs[buf][0] + dst[i]);
    }
  };

  const int NS = K / 32;
  stage(0, 0);
  for (int s = 0; s < NS; s++) {
    const int cur = s & 1;
    const bool lastit = (s == NS - 1);
    if (!lastit) stage(cur ^ 1, s + 1);
    if (!lastit) VMCNT8(); else VMCNT0();
    SBAR();
    SCHED0();
    bf16x8 ah[4], al[4], bh[4], bl[4];
    const int g = l >> 4;
    if (APK) {
      const u32* At = (const u32*)&As[cur][0];
#pragma unroll
      for (int mi = 0; mi < 4; mi++) {
        int row = wr + mi * 16 + (l & 15);
        u32 t[8];
        *(uint4*)t = *(const uint4*)&At[row * 32 + (((2 * g) ^ (row & 7)) * 4)];
        *(uint4*)(t + 4) = *(const uint4*)&At[row * 32 + (((2 * g + 1) ^ (row & 7)) * 4)];
        unpack8(t, ah[mi], al[mi]);
      }
    } else {
#pragma unroll
      for (int mi = 0; mi < 4; mi++) {
        int row = wr + mi * 16 + (l & 15);
        ah[mi] = *(const bf16x8*)&As[cur][row * 64 + ((g ^ (row & 7)) * 8)];
        al[mi] = *(const bf16x8*)&As[cur][row * 64 + (((4 + g) ^ (row & 7)) * 8)];
      }
    }
#pragma unroll
    for (int ni = 0; ni < 4; ni++) {
      int row = wc + ni * 16 + (l & 15);
      bh[ni] = *(const bf16x8*)&Bs[cur][row * 64 + ((g ^ (row & 7)) * 8)];
      bl[ni] = *(const bf16x8*)&Bs[cur][row * 64 + (((4 + g) ^ (row & 7)) * 8)];
    }
#pragma unroll
    for (int mi = 0; mi < 4; mi++)
#pragma unroll
      for (int ni = 0; ni < 4; ni++) {
        f32x4 c = acc[mi][ni];
        c = MFMA_BF16(al[mi], bh[ni], c);
        c = MFMA_BF16(ah[mi], bl[ni], c);
        c = MFMA_BF16(ah[mi], bh[ni], c);
        acc[mi][ni] = c;
      }
    SCHED0();
    if (!lastit) SBAR();
  }

  if (OUT == 0) {
    u32* dstp;
    int nb;
    if (n0 < 1024) { dstp = oq; nb = n0; }
    else if (n0 < 2048) { dstp = ok; nb = n0 - 1024; }
    else { dstp = ov; nb = n0 - 2048; }
#pragma unroll
    for (int mi = 0; mi < 4; mi++)
#pragma unroll
      for (int ni = 0; ni < 4; ni++)
#pragma unroll
        for (int r = 0; r < 4; r++) {
          int row = m0 + wr + mi * 16 + ((l >> 4) << 2) + r;
          int col = nb + wc + ni * 16 + (l & 15);
          dstp[(size_t)row * 1024 + col] = pack_hl(acc[mi][ni][r]);
        }
  } else {
#pragma unroll
    for (int mi = 0; mi < 4; mi++)
#pragma unroll
      for (int ni = 0; ni < 4; ni++)
#pragma unroll
        for (int r = 0; r < 4; r++) {
          int row = m0 + wr + mi * 16 + ((l >> 4) << 2) + r;
          int col = n0 + wc + ni * 16 + (l & 15);
          of[(size_t)row * 1024 + col] = resid[(size_t)row * 1024 + col] + acc[mi][ni][r];
        }
  }
}

// ---------- flash attention, kt-chunked (validated round-6 version) ----------
__global__ __launch_bounds__(256) void attn_kernel(
    const u32* __restrict__ Qp, const u32* __restrict__ Kp, const u32* __restrict__ Vp,
    float* __restrict__ Opart, float* __restrict__ mpart, float* __restrict__ lpart) {
  constexpr int LDK = 68;
  __shared__ u32 Ks[64 * LDK];
  __shared__ u32 Vs[64 * LDK];
  __shared__ u32 Ps[64 * LDK];
  const int tid = threadIdx.x, w = tid >> 6, l = tid & 63;
  int b = blockIdx.x, qt, c;
  if (b < 8) { qt = b; c = 0; }
  else if (b < 24) { qt = 8 + ((b - 8) >> 1); c = (b - 8) & 1; }
  else if (b < 48) { qt = 16 + (b - 24) / 3; c = (b - 24) % 3; }
  else { qt = 24 + ((b - 48) >> 2); c = (b - 48) & 3; }
  const int hh = blockIdx.y;
  const int q0 = qt * 64, hc = hh * 64;
  const int kt0 = c * kChunk;
  const int kt1 = min(kt0 + kChunk, qt + 1);

  bf16x8 qh[2], ql[2];
  {
    const int qrow = q0 + w * 16 + (l & 15);
#pragma unroll
    for (int kk = 0; kk < 2; kk++) {
      u32 t[8];
      const u32* p = Qp + (size_t)qrow * kD + hc + kk * 32 + ((l >> 4) << 3);
      *(uint4*)t = *(const uint4*)p;
      *(uint4*)(t + 4) = *(const uint4*)(p + 4);
      unpack8(t, qh[kk], ql[kk]);
    }
  }
  float mrun[4], lrun[4];
  f32x4 zero = {0.f, 0.f, 0.f, 0.f};
  f32x4 oacc[4];
#pragma unroll
  for (int r = 0; r < 4; r++) { mrun[r] = -3.0e38f; lrun[r] = 0.f; }
#pragma unroll
  for (int vb = 0; vb < 4; vb++) oacc[vb] = zero;

  const int trow = tid >> 2, c0v = (tid & 3) * 16;
  const u32* gKb = Kp + hc + c0v;
  const u32* gVb = Vp + hc + c0v;
  uint4 kr[4], vr[4];
  {
    const u32* gK = gKb + (size_t)(kt0 * 64 + trow) * kD;
    kr[0] = *(const uint4*)gK; kr[1] = *(const uint4*)(gK + 4);
    kr[2] = *(const uint4*)(gK + 8); kr[3] = *(const uint4*)(gK + 12);
    const u32* gV = gVb + (size_t)(kt0 * 64 + trow) * kD;
    vr[0] = *(const uint4*)gV; vr[1] = *(const uint4*)(gV + 4);
    vr[2] = *(const uint4*)(gV + 8); vr[3] = *(const uint4*)(gV + 12);
  }

  for (int kt = kt0; kt < kt1; kt++) {
    {
      u32* sK = Ks + trow * LDK + c0v;
      *(uint4*)sK = kr[0]; *(uint4*)(sK + 4) = kr[1];
      *(uint4*)(sK + 8) = kr[2]; *(uint4*)(sK + 12) = kr[3];
#pragma unroll
      for (int j = 0; j < 4; j++) {
        Vs[(c0v + j * 4 + 0) * LDK + trow] = vr[j].x;
        Vs[(c0v + j * 4 + 1) * LDK + trow] = vr[j].y;
        Vs[(c0v + j * 4 + 2) * LDK + trow] = vr[j].z;
        Vs[(c0v + j * 4 + 3) * LDK + trow] = vr[j].w;
      }
    }
    __syncthreads();
    if (kt + 1 < kt1) {
      const u32* gK = gKb + (size_t)((kt + 1) * 64 + trow) * kD;
      kr[0] = *(const uint4*)gK; kr[1] = *(const uint4*)(gK + 4);
      kr[2] = *(const uint4*)(gK + 8); kr[3] = *(const uint4*)(gK + 12);
      const u32* gV = gVb + (size_t)((kt + 1) * 64 + trow) * kD;
      vr[0] = *(const uint4*)gV; vr[1] = *(const uint4*)(gV + 4);
      vr[2] = *(const uint4*)(gV + 8); vr[3] = *(const uint4*)(gV + 12);
    }

    f32x4 sfr[4];
#pragma unroll
    for (int kb = 0; kb < 4; kb++) {
      f32x4 sa = zero;
#pragma unroll
      for (int kk = 0; kk < 2; kk++) {
        u32 t[8];
        bf16x8 kh, kl;
        const u32* p = Ks + (kb * 16 + (l & 15)) * LDK + kk * 32 + ((l >> 4) << 3);
        *(uint4*)t = *(const uint4*)p;
        *(uint4*)(t + 4) = *(const uint4*)(p + 4);
        unpack8(t, kh, kl);
        sa = MFMA_BF16(ql[kk], kl, sa);
        sa = MFMA_BF16(ql[kk], kh, sa);
        sa = MFMA_BF16(qh[kk], kl, sa);
        sa = MFMA_BF16(qh[kk], kh, sa);
      }
      sfr[kb] = sa * 0.125f;
    }
    if (kt == qt) {
#pragma unroll
      for (int kb = 0; kb < 4; kb++) {
        int t = kt * 64 + kb * 16 + (l & 15);
#pragma unroll
        for (int r = 0; r < 4; r++) {
          int qq = q0 + w * 16 + ((l >> 4) << 2) + r;
          if (t > qq) sfr[kb][r] = -3.0e38f;
        }
      }
    }
#pragma unroll
    for (int r = 0; r < 4; r++) {
      float mx = fmaxf(fmaxf(sfr[0][r], sfr[1][r]), fmaxf(sfr[2][r], sfr[3][r]));
#pragma unroll
      for (int mm = 1; mm < 16; mm <<= 1) mx = fmaxf(mx, __shfl_xor(mx, mm));
      float mnew = fmaxf(mrun[r], mx);
      float sf = __expf(mrun[r] - mnew);
      mrun[r] = mnew;
      float rs = 0.f;
#pragma unroll
      for (int kb = 0; kb < 4; kb++) {
        float p = __expf(sfr[kb][r] - mnew);
        sfr[kb][r] = p;
        rs += p;
      }
#pragma unroll
      for (int mm = 1; mm < 16; mm <<= 1) rs += __shfl_xor(rs, mm);
      lrun[r] = lrun[r] * sf + rs;
#pragma unroll
      for (int vb = 0; vb < 4; vb++) oacc[vb][r] *= sf;
    }
#pragma unroll
    for (int kb = 0; kb < 4; kb++)
#pragma unroll
      for (int r = 0; r < 4; r++)
        Ps[(w * 16 + ((l >> 4) << 2) + r) * LDK + kb * 16 + (l & 15)] = pack_hl(sfr[kb][r]);
#pragma unroll
    for (int ks = 0; ks < 2; ks++) {
      bf16x8 ph, pl;
      {
        u32 t[8];
        const u32* pp = Ps + (w * 16 + (l & 15)) * LDK + ks * 32 + ((l >> 4) << 3);
        *(uint4*)t = *(const uint4*)pp;
        *(uint4*)(t + 4) = *(const uint4*)(pp + 4);
        unpack8(t, ph, pl);
      }
#pragma unroll
      for (int vb = 0; vb < 4; vb++) {
        u32 t2[8];
        bf16x8 vh, vl;
        const u32* pv = Vs + (vb * 16 + (l & 15)) * LDK + ks * 32 + ((l >> 4) << 3);
        *(uint4*)t2 = *(const uint4*)pv;
        *(uint4*)(t2 + 4) = *(const uint4*)(pv + 4);
        unpack8(t2, vh, vl);
        f32x4 cc = oacc[vb];
        cc = MFMA_BF16(pl, vl, cc);
        cc = MFMA_BF16(pl, vh, cc);
        cc = MFMA_BF16(ph, vl, cc);
        cc = MFMA_BF16(ph, vh, cc);
        oacc[vb] = cc;
      }
    }
    __syncthreads();
  }

  const int p = (qt * 16 + hh) * 4 + c;
  float* Po = Opart + (size_t)p * 4096;
#pragma unroll
  for (int vb = 0; vb < 4; vb++)
#pragma unroll
    for (int r = 0; r < 4; r++) {
      int rl = w * 16 + ((l >> 4) << 2) + r;
      int cl = vb * 16 + (l & 15);
      Po[rl * 64 + cl] = oacc[vb][r];
    }
  if ((l & 15) == 0) {
#pragma unroll
    for (int r = 0; r < 4; r++) {
      int rl = w * 16 + ((l >> 4) << 2) + r;
      mpart[p * 64 + rl] = mrun[r];
      lpart[p * 64 + rl] = lrun[r];
    }
  }
}

// ---------- merge chunk partials -> packed ctx ----------
__global__ __launch_bounds__(256) void attn_merge(
    const float* __restrict__ Opart, const float* __restrict__ mpart,
    const float* __restrict__ lpart, u32* __restrict__ Op) {
  const int qt = blockIdx.x, hh = blockIdx.y;
  const int nch = (qt + kChunk) >> 3;
  const int t = threadIdx.x;
  const int row = t >> 2;
  const int c0 = (t & 3) * 16;
  const int pbase = (qt * 16 + hh) * 4;
  float M = -3.0e38f;
  for (int c = 0; c < nch; c++) M = fmaxf(M, mpart[(pbase + c) * 64 + row]);
  float den = 0.f;
  float acc[16];
#pragma unroll
  for (int j = 0; j < 16; j++) acc[j] = 0.f;
  for (int c = 0; c < nch; c++) {
    float wgt = __expf(mpart[(pbase + c) * 64 + row] - M);
    den += wgt * lpart[(pbase + c) * 64 + row];
    const float* po = Opart + (size_t)(pbase + c) * 4096 + row * 64 + c0;
#pragma unroll
    for (int j = 0; j < 16; j += 4) {
      float4 v = *(const float4*)(po + j);
      acc[j] += wgt * v.x; acc[j + 1] += wgt * v.y;
      acc[j + 2] += wgt * v.z; acc[j + 3] += wgt * v.w;
    }
  }
  float inv = 1.f / den;
  u32* dst = Op + (size_t)(qt * 64 + row) * kD + hh * 64 + c0;
#pragma unroll
  for (int j = 0; j < 16; j++) dst[j] = pack_hl(acc[j] * inv);
}

// ---------- router ----------
__global__ __launch_bounds__(256) void router_kernel(
    const float* __restrict__ normed, const float* __restrict__ Wg,
    float* __restrict__ probs, float* __restrict__ gates,
    int* __restrict__ experts, int* __restrict__ counts) {
  const int w = threadIdx.x >> 6, l = threadIdx.x & 63;
  const int s = blockIdx.x * 4 + w;
  float lg[kE];
  const float* row = normed + (size_t)s * kD;
#pragma unroll
  for (int e = 0; e < kE; e++) {
    const float* wg = Wg + (size_t)e * kD;
    float a = 0.f;
    for (int d = l; d < kD; d += 64) a += row[d] * wg[d];
#pragma unroll
    for (int m = 32; m; m >>= 1) a += __shfl_xor(a, m);
    lg[e] = a;
  }
  if (l == 0) {
    float mx = lg[0];
#pragma unroll
    for (int e = 1; e < kE; e++) mx = fmaxf(mx, lg[e]);
    float p[kE], sum = 0.f;
#pragma unroll
    for (int e = 0; e < kE; e++) { p[e] = __expf(lg[e] - mx); sum += p[e]; }
    float inv = 1.f / sum;
#pragma unroll
    for (int e = 0; e < kE; e++) { p[e] *= inv; probs[(size_t)s * kE + e] = p[e]; }
    int i1 = 0;
#pragma unroll
    for (int e = 1; e < kE; e++) if (lg[e] > lg[i1]) i1 = e;
    int i2 = (i1 == 0) ? 1 : 0;
#pragma unroll
    for (int e = 0; e < kE; e++) if (e != i1 && lg[e] > lg[i2]) i2 = e;
    float den = 1.f / (p[i1] + p[i2]);
    gates[s * 2] = p[i1] * den;
    gates[s * 2 + 1] = p[i2] * den;
    experts[s * 2] = i1;
    experts[s * 2 + 1] = i2;
    atomicAdd(&counts[i1], 1);
    atomicAdd(&counts[i2], 1);
  }
}

__global__ void moe_init(int* counts) {
  if (threadIdx.x < kE) counts[threadIdx.x] = 0;
}
__global__ void moe_scan(const int* __restrict__ counts, int* __restrict__ ebase,
                         int* __restrict__ cursor, int2* __restrict__ tmap) {
  if (threadIdx.x == 0) {
    int acc = 0, t = 0;
    for (int e = 0; e < kE; e++) {
      ebase[e] = acc;
      cursor[e] = acc;
      int nt = (counts[e] + 127) >> 7;
      for (int i = 0; i < nt; i++) tmap[t++] = make_int2(e, i * 128);
      acc += nt << 7;
    }
    ebase[kE] = acc;
    for (; t < kMaxTiles; t++) tmap[t] = make_int2(-1, 0);
  }
}
__global__ void moe_fill(const int* __restrict__ experts, int* __restrict__ cursor,
                         int* __restrict__ slot_list, int* __restrict__ slot_of) {
  int s = blockIdx.x * 256 + threadIdx.x;
  if (s >= kS) return;
  for (int k = 0; k < 2; k++) {
    int e = experts[s * 2 + k];
    int pos = atomicAdd(&cursor[e], 1);
    slot_list[pos] = s;
    slot_of[s * 2 + k] = pos;
  }
}

// ---------- MoE GEMM A: fused gelu, f32 weights DIRECT, BK=32 + XCD swizzle (T1) ----------
// Bijective chunked remap (2560 % 8 == 0): blocks dispatched round-robin to XCDs get
// contiguous logical chunks; logical order lid = nx*40 + ty groups the 40 tiles that
// share each n-block's B panels (and reuses A panels 8x) within one XCD's L2.
__global__ __launch_bounds__(256) void moe_mmA(
    const u16* __restrict__ A, const float* __restrict__ Wi, const float* __restrict__ Wv2,
    const int* __restrict__ slot_list, const int* __restrict__ counts,
    const int* __restrict__ ebase, const int2* __restrict__ tmap,
    u16* __restrict__ H) {
  // XCD-aware swizzle: gridDim = (64, 40); bid linear (x fastest)
  const int bid = blockIdx.y * 64 + blockIdx.x;           // 0..2559
  const int lid = (bid & 7) * 320 + (bid >> 3);           // chunked per-XCD
  const int nx = lid / 40;                                // n-block 0..63
  const int ty = lid % 40;                                // tile 0..39
  int2 tm = tmap[ty];
  const int e = tm.x;
  if (e < 0) return;
  const int base = ebase[e], Me = counts[e], m0 = tm.y;
  const int n0 = nx * 128;  // interleaved col base (0..8191)
  __shared__ u16 As[2][64 * 64];    // 8 KB per buffer
  __shared__ float Bsf[2][128 * 32];  // 16 KB per buffer
  const int tid = threadIdx.x, w = tid >> 6, l = tid & 63;
  const int wr = (w >> 1) * 64, wc = (w & 1) * 64;
  const char* Ab = (const char*)A;

  size_t asrc[2];
  int adst[2];
#pragma unroll
  for (int i = 0; i < 2; i++) {
    int fl = i * 256 + tid;
    int lrow = fl >> 3, sl = fl & 7;
    int sp = sl ^ (lrow & 7);
    int t = 2 * lrow + (sp >> 2);
    int cbl = sp & 3;
    int mr = m0 + t;
    if (mr > Me - 1) mr = Me - 1;
    int ar = slot_list[base + mr];
    asrc[i] = (size_t)ar * 2048 + (size_t)cbl * 16;
    adst[i] = fl * 16;
  }
  const char* bptr[4];
  int bdst[4];
#pragma unroll
  for (int i = 0; i < 4; i++) {
    int fl = i * 256 + tid;
    int row = fl >> 3, sl = fl & 7;
    int sp = sl ^ (row & 7);
    int nn = n0 + row;
    const float* srcT = (nn & 1) ? Wv2 : Wi;
    bptr[i] = (const char*)(srcT + ((size_t)e * 4096 + (nn >> 1)) * 1024) + sp * 16;
    bdst[i] = fl * 16;
  }

  const int g = l >> 4;
  int aoff[4], boff0[4], boff1[4];
#pragma unroll
  for (int mi = 0; mi < 4; mi++) {
    int t = wr + mi * 16 + (l & 15);
    int lr = t >> 1;
    int sl = (((t & 1) << 2) | g) ^ (lr & 7);
    aoff[mi] = lr * 128 + sl * 16;
  }
#pragma unroll
  for (int ni = 0; ni < 4; ni++) {
    int rr = wc + ni * 16 + (l & 15);
    boff0[ni] = rr * 128 + (((2 * g) ^ (rr & 7)) * 16);
    boff1[ni] = rr * 128 + (((2 * g + 1) ^ (rr & 7)) * 16);
  }

  f32x4 zero = {0.f, 0.f, 0.f, 0.f};
  f32x4 acc[4][4];
#pragma unroll
  for (int i = 0; i < 4; i++)
#pragma unroll
    for (int j = 0; j < 4; j++) acc[i][j] = zero;

  auto stage = [&](int buf, int s) {
    const size_t soA = (size_t)s * 64;
    const size_t soB = (size_t)s * 128;
#pragma unroll
    for (int i = 0; i < 2; i++)
      gload_lds16(Ab + soA + asrc[i], (char*)&As[buf][0] + adst[i]);
#pragma unroll
    for (int i = 0; i < 4; i++)
      gload_lds16(bptr[i] + soB, (char*)&Bsf[buf][0] + bdst[i]);
  };

  const int NS = kD / 32;  // 32
  stage(0, 0);
  for (int s = 0; s < NS; s++) {
    const int cur = s & 1;
    const bool lastit = (s == NS - 1);
    if (!lastit) stage(cur ^ 1, s + 1);
    if (!lastit) VMCNT6(); else VMCNT0();
    SBAR();
    SCHED0();
    const char* Ac = (const char*)&As[cur][0];
    const char* Bc = (const char*)&Bsf[cur][0];
    bf16x8 af[4], bfr[4];
#pragma unroll
    for (int mi = 0; mi < 4; mi++) af[mi] = *(const bf16x8*)(Ac + aoff[mi]);
#pragma unroll
    for (int ni = 0; ni < 4; ni++) {
      float4 f0 = *(const float4*)(Bc + boff0[ni]);
      float4 f1 = *(const float4*)(Bc + boff1[ni]);
      u32 pk[4];
      pk[0] = cvtpk(f0.x, f0.y);
      pk[1] = cvtpk(f0.z, f0.w);
      pk[2] = cvtpk(f1.x, f1.y);
      pk[3] = cvtpk(f1.z, f1.w);
      bfr[ni] = *(bf16x8*)pk;
    }
#pragma unroll
    for (int mi = 0; mi < 4; mi++)
#pragma unroll
      for (int ni = 0; ni < 4; ni++) acc[mi][ni] = MFMA_BF16(af[mi], bfr[ni], acc[mi][ni]);
    SCHED0();
    if (!lastit) SBAR();
  }

#pragma unroll
  for (int mi = 0; mi < 4; mi++)
#pragma unroll
    for (int r = 0; r < 4; r++) {
      int ml = m0 + wr + mi * 16 + ((l >> 4) << 2) + r;
      if (ml >= Me) continue;
      size_t rb = (size_t)(base + ml) * 4096;
#pragma unroll
      for (int ni = 0; ni < 4; ni++) {
        int col = n0 + wc + ni * 16 + (l & 15);
        float v0 = acc[mi][ni][r];
        float pv = __shfl_xor(v0, 1);
        if ((l & 1) == 0) {
          float ge = 0.5f * v0 * (1.0f + erff(v0 * 0.70710678118654752f));
          H[rb + (col >> 1)] = bf16_rne(ge * pv);
        }
      }
    }
}

// ---------- MoE GEMM 2: N=64, reg-staged single-barrier pipeline (round-14/15/17 validated) ----------
__global__ __launch_bounds__(256) void moe_mm2(
    const u16* __restrict__ H, const float* __restrict__ Wo_f,
    const int* __restrict__ counts, const int* __restrict__ ebase,
    const int2* __restrict__ tmap, float* __restrict__ eo) {
  int2 tm = tmap[blockIdx.y];
  const int e = tm.x;
  if (e < 0) return;
  const int base = ebase[e], Me = counts[e], m0 = tm.y;
  const int n0 = blockIdx.x * 64;
  __shared__ u16 As[2][64 * 64];  // 8 KB per buffer (128 tile rows paired)
  __shared__ u16 Bs[2][32 * 64];  // 4 KB per buffer (64 tile rows paired)
  const int tid = threadIdx.x, w = tid >> 6, l = tid & 63;
  const int wr = (w >> 1) * 64, wc = (w & 1) * 32;

  const int srow = tid >> 1, sh = tid & 1;
  int mrA = m0 + srow;
  if (mrA > Me - 1) mrA = Me - 1;
  const u16* agp = H + (size_t)(base + mrA) * 4096 + sh * 16;  // +s*32 per step
  const int wlA = srow >> 1;
  const int awo0 = wlA * 128 + (((((srow & 1) << 2) | (sh * 2)) ^ (wlA & 7)) * 16);
  const int awo1 = wlA * 128 + (((((srow & 1) << 2) | (sh * 2 + 1)) ^ (wlA & 7)) * 16);
  const int brow = tid >> 2, bq = tid & 3;
  const float* bgp = Wo_f + ((size_t)e * 1024 + n0 + brow) * 4096 + bq * 8;  // +s*32
  const int wlB = brow >> 1;
  const int bwo = wlB * 128 + (((((brow & 1) << 2) | bq) ^ (wlB & 7)) * 16);

  const int g = l >> 4;
  int aoff[4], boff[2];
#pragma unroll
  for (int mi = 0; mi < 4; mi++) {
    int t = wr + mi * 16 + (l & 15);
    int lr = t >> 1;
    aoff[mi] = lr * 128 + (((((t & 1) << 2) | g) ^ (lr & 7)) * 16);
  }
#pragma unroll
  for (int ni = 0; ni < 2; ni++) {
    int t = wc + ni * 16 + (l & 15);
    int lr = t >> 1;
    boff[ni] = lr * 128 + (((((t & 1) << 2) | g) ^ (lr & 7)) * 16);
  }

  f32x4 zero = {0.f, 0.f, 0.f, 0.f};
  f32x4 acc[4][2];
#pragma unroll
  for (int i = 0; i < 4; i++)
#pragma unroll
    for (int j = 0; j < 2; j++) acc[i][j] = zero;

  // prologue: stage step 0 into buf 0
  uint4 a0 = *(const uint4*)agp;
  uint4 a1 = *(const uint4*)(agp + 8);
  float4 b0 = *(const float4*)bgp;
  float4 b1 = *(const float4*)(bgp + 4);
  {
    *(uint4*)((char*)&As[0][0] + awo0) = a0;
    *(uint4*)((char*)&As[0][0] + awo1) = a1;
    u32 pk[4];
    pk[0] = cvtpk(b0.x, b0.y); pk[1] = cvtpk(b0.z, b0.w);
    pk[2] = cvtpk(b1.x, b1.y); pk[3] = cvtpk(b1.z, b1.w);
    *(uint4*)((char*)&Bs[0][0] + bwo) = *(uint4*)pk;
  }
  LGKM0();
  SBAR();
  SCHED0();

  const int NS = kFF / 32;  // 128
  for (int s = 0; s < NS; s++) {
    const int cur = s & 1;
    const bool more = (s + 1 < NS);
    if (more) {
      const u16* ap = agp + (s + 1) * 32;
      a0 = *(const uint4*)ap;
      a1 = *(const uint4*)(ap + 8);
      const float* bp = bgp + (s + 1) * 32;
      b0 = *(const float4*)bp;
      b1 = *(const float4*)(bp + 4);
    }
    SCHED0();
    const char* Ac = (const char*)&As[cur][0];
    const char* Bc = (const char*)&Bs[cur][0];
    bf16x8 af[4], bfr[2];
#pragma unroll
    for (int mi = 0; mi < 4; mi++) af[mi] = *(const bf16x8*)(Ac + aoff[mi]);
#pragma unroll
    for (int ni = 0; ni < 2; ni++) bfr[ni] = *(const bf16x8*)(Bc + boff[ni]);
#pragma unroll
    for (int mi = 0; mi < 4; mi++)
#pragma unroll
      for (int ni = 0; ni < 2; ni++) acc[mi][ni] = MFMA_BF16(af[mi], bfr[ni], acc[mi][ni]);
    if (more) {
      char* Aw = (char*)&As[cur ^ 1][0];
      char* Bw = (char*)&Bs[cur ^ 1][0];
      *(uint4*)(Aw + awo0) = a0;
      *(uint4*)(Aw + awo1) = a1;
      u32 pk[4];
      pk[0] = cvtpk(b0.x, b0.y); pk[1] = cvtpk(b0.z, b0.w);
      pk[2] = cvtpk(b1.x, b1.y); pk[3] = cvtpk(b1.z, b1.w);
      *(uint4*)(Bw + bwo) = *(uint4*)pk;
      LGKM0();
      SBAR();
      SCHED0();
    }
  }

#pragma unroll
  for (int mi = 0; mi < 4; mi++)
#pragma unroll
    for (int r = 0; r < 4; r++) {
      int ml = m0 + wr + mi * 16 + ((l >> 4) << 2) + r;
      if (ml >= Me) continue;
      size_t rb = (size_t)(base + ml) * kD;
#pragma unroll
      for (int ni = 0; ni < 2; ni++) {
        int col = n0 + wc + ni * 16 + (l & 15);
        eo[rb + col] = acc[mi][ni][r];
      }
    }
}

// ---------- final combine ----------
__global__ __launch_bounds__(256) void combine_kernel(
    const float* __restrict__ h, const float* __restrict__ eo,
    const float* __restrict__ gates, const int* __restrict__ slot_of,
    float* __restrict__ out) {
  const int s = blockIdx.x;
  const float g0 = gates[s * 2], g1 = gates[s * 2 + 1];
  const int p0 = slot_of[s * 2], p1 = slot_of[s * 2 + 1];
  const int c = threadIdx.x * 4;
  float4 hv = *(const float4*)(h + (size_t)s * kD + c);
  float4 e0 = *(const float4*)(eo + (size_t)p0 * kD + c);
  float4 e1 = *(const float4*)(eo + (size_t)p1 * kD + c);
  float4 o;
  o.x = hv.x + g0 * e0.x + g1 * e1.x;
  o.y = hv.y + g0 * e0.y + g1 * e1.y;
  o.z = hv.z + g0 * e0.z + g1 * e1.z;
  o.w = hv.w + g0 * e0.w + g1 * e1.w;
  *(float4*)(out + (size_t)s * kD + c) = o;
}

extern "C" void kernel_launch(void* const* d_in, const int* in_sizes, int n_in,
                              void* d_out, int out_size, void* d_ws, size_t ws_size,
                              hipStream_t stream) {
  (void)in_sizes; (void)n_in; (void)out_size; (void)ws_size;
  const float* x = (const float*)d_in[0];
  const float* scale_attn = (const float*)d_in[2];
  const float* Wq = (const float*)d_in[3];
  const float* Wk = (const float*)d_in[4];
  const float* Wv = (const float*)d_in[5];
  const float* Wo = (const float*)d_in[6];
  const float* scale_ffn = (const float*)d_in[7];
  const float* Wg = (const float*)d_in[8];
  const float* W_in = (const float*)d_in[9];
  const float* W_vv = (const float*)d_in[10];
  const float* W_out = (const float*)d_in[11];
  float* out = (float*)d_out;
  float* probs = out + (size_t)kS * kD;

  char* wsb = (char*)d_ws;
  size_t off = 0;
  auto alloc = [&](size_t bytes) -> void* {
    void* p = wsb + off;
    off += (bytes + 255) & ~(size_t)255;
    return p;
  };
  const size_t SDu = (size_t)kS * kD;
  u16* normA_dp = (u16*)alloc(SDu * 4);
  u32* qpk = (u32*)alloc(SDu * 4);
  u32* kpk = (u32*)alloc(SDu * 4);
  u32* vpk = (u32*)alloc(SDu * 4);
  u32* ctxpk = (u32*)alloc(SDu * 4);
  u16* Wqkv_dp = (u16*)alloc((size_t)3072 * 2048 * 2);
  u16* Wo_dp = (u16*)alloc((size_t)1024 * 2048 * 2);
  float* normFf = (float*)alloc(SDu * 4);
  float* eo = (float*)alloc((size_t)kSlotCap * kD * 4);
  float* h = (float*)alloc(SDu * 4);
  u16* normFb = (u16*)alloc(SDu * 2);
  u16* H = (u16*)alloc((size_t)kSlotCap * kFF * 2);
  float* Opart = (float*)alloc((size_t)2048 * 4096 * 4);
  float* mpart = (float*)alloc((size_t)2048 * 64 * 4);
  float* lpart = (float*)alloc((size_t)2048 * 64 * 4);
  float* gates = (float*)alloc(kS * 2 * 4);
  int* experts = (int*)alloc(kS * 2 * 4);
  int* slot_of = (int*)alloc(kS * 2 * 4);
  int* slot_list = (int*)alloc(kSlotCap * 4);
  int* counts = (int*)alloc(64);
  int* ebase = (int*)alloc(64);
  int* cursor = (int*)alloc(64);
  int2* tmap = (int2*)alloc(kMaxTiles * 8);

  pack_dp3<<<(3072 * 1024) / 256, 256, 0, stream>>>(Wq, Wk, Wv, Wqkv_dp);
  pack_dp1<<<(1024 * 1024) / 256, 256, 0, stream>>>(Wo, Wo_dp, 1024 * 1024);

  rmsnorm_kernel<0><<<kS, 256, 0, stream>>>(x, scale_attn, normA_dp, nullptr, nullptr);
  gemm_dp<0, 0><<<dim3(3072 / 128, kS / 128), 256, 0, stream>>>(
      normA_dp, Wqkv_dp, nullptr, kD, qpk, kpk, vpk, nullptr);
  attn_kernel<<<dim3(80, kH), 256, 0, stream>>>(qpk, kpk, vpk, Opart, mpart, lpart);
  attn_merge<<<dim3(kS / 64, kH), 256, 0, stream>>>(Opart, mpart, lpart, ctxpk);
  gemm_dp<1, 1><<<dim3(1024 / 128, kS / 128), 256, 0, stream>>>(
      ctxpk, Wo_dp, x, kD, nullptr, nullptr, nullptr, h);

  rmsnorm_kernel<1><<<kS, 256, 0, stream>>>(h, scale_ffn, nullptr, normFf, normFb);
  moe_init<<<1, 64, 0, stream>>>(counts);
  router_kernel<<<kS / 4, 256, 0, stream>>>(normFf, Wg, probs, gates, experts, counts);
  moe_scan<<<1, 64, 0, stream>>>(counts, ebase, cursor, tmap);
  moe_fill<<<kS / 256, 256, 0, stream>>>(experts, cursor, slot_list, slot_of);

  moe_mmA<<<dim3(64, kMaxTiles), 256, 0, stream>>>(
      normFb, W_in, W_vv, slot_list, counts, ebase, tmap, H);
  moe_mm2<<<dim3(kD / 64, kMaxTiles), 256, 0, stream>>>(
      H, W_out, counts, ebase, tmap, eo);

  combine_kernel<<<kS, 256, 0, stream>>>(h, eo, gates, slot_of, out);
}